// Round 1
// baseline (1980.053 us; speedup 1.0000x reference)
//
#include <hip/hip_runtime.h>
#include <math.h>

#define BATCH 4
#define SEQ 2048
#define NDIM 1024
#define HEADS 16
#define DHEAD 64
#define NROWS (BATCH * SEQ)     // 8192
#define QKVN (3 * NDIM)         // 3072
#define LNEPS 1e-5f

// ---------------- K1: LayerNorm row stats over DIM=1024 ----------------
__global__ __launch_bounds__(256) void ln_stats_kernel(const float* __restrict__ x,
                                                       float* __restrict__ mu,
                                                       float* __restrict__ rs) {
    int row = blockIdx.x;
    const float* xr = x + (size_t)row * NDIM;
    float s = 0.f, ss = 0.f;
    for (int i = threadIdx.x; i < NDIM; i += 256) {
        float v = xr[i];
        s += v;
        ss += v * v;
    }
#pragma unroll
    for (int m = 32; m >= 1; m >>= 1) {
        s += __shfl_xor(s, m);
        ss += __shfl_xor(ss, m);
    }
    __shared__ float r0[4], r1[4];
    int wid = threadIdx.x >> 6;
    if ((threadIdx.x & 63) == 0) { r0[wid] = s; r1[wid] = ss; }
    __syncthreads();
    if (threadIdx.x == 0) {
        float S = r0[0] + r0[1] + r0[2] + r0[3];
        float SS = r1[0] + r1[1] + r1[2] + r1[3];
        float m_ = S * (1.f / NDIM);
        float var = SS * (1.f / NDIM) - m_ * m_;
        mu[row] = m_;
        rs[row] = rsqrtf(var + LNEPS);
    }
}

// ---------------- K2: QKV GEMM with fused input LayerNorm ----------------
// C[8192,3072] = LN(x) @ w_qkv, scattered into q/k/v buffers [B*H][SEQ][DHEAD]
__global__ __launch_bounds__(256) void qkv_gemm_kernel(
    const float* __restrict__ x, const float* __restrict__ mu, const float* __restrict__ rs,
    const float* __restrict__ lng, const float* __restrict__ lnb,
    const float* __restrict__ w,
    float* __restrict__ qb, float* __restrict__ kb, float* __restrict__ vb) {
    __shared__ float As[16][132];  // [k][m], LN applied
    __shared__ float Bs[16][132];  // [k][n]
    const int t = threadIdx.x;
    const int m0 = blockIdx.x * 128;
    const int n0 = blockIdx.y * 128;
    const int tx = t & 15, ty = t >> 4;

    const int arow0 = t >> 2;
    const int arow1 = 64 + (t >> 2);
    const int ac = (t & 3) * 4;
    const float amu0 = mu[m0 + arow0], ars0 = rs[m0 + arow0];
    const float amu1 = mu[m0 + arow1], ars1 = rs[m0 + arow1];
    const int brow = t >> 5;
    const int bc = (t & 31) * 4;

    float acc[8][8];
#pragma unroll
    for (int i = 0; i < 8; i++)
#pragma unroll
        for (int j = 0; j < 8; j++) acc[i][j] = 0.f;

    for (int k0 = 0; k0 < NDIM; k0 += 16) {
        float4 a0 = *(const float4*)&x[(size_t)(m0 + arow0) * NDIM + k0 + ac];
        float4 a1 = *(const float4*)&x[(size_t)(m0 + arow1) * NDIM + k0 + ac];
        float4 gv = *(const float4*)&lng[k0 + ac];
        float4 bv = *(const float4*)&lnb[k0 + ac];
        float4 b0 = *(const float4*)&w[(size_t)(k0 + brow) * QKVN + n0 + bc];
        float4 b1 = *(const float4*)&w[(size_t)(k0 + brow + 8) * QKVN + n0 + bc];
        __syncthreads();
        As[ac + 0][arow0] = (a0.x - amu0) * ars0 * gv.x + bv.x;
        As[ac + 1][arow0] = (a0.y - amu0) * ars0 * gv.y + bv.y;
        As[ac + 2][arow0] = (a0.z - amu0) * ars0 * gv.z + bv.z;
        As[ac + 3][arow0] = (a0.w - amu0) * ars0 * gv.w + bv.w;
        As[ac + 0][arow1] = (a1.x - amu1) * ars1 * gv.x + bv.x;
        As[ac + 1][arow1] = (a1.y - amu1) * ars1 * gv.y + bv.y;
        As[ac + 2][arow1] = (a1.z - amu1) * ars1 * gv.z + bv.z;
        As[ac + 3][arow1] = (a1.w - amu1) * ars1 * gv.w + bv.w;
        *(float4*)&Bs[brow][bc] = b0;
        *(float4*)&Bs[brow + 8][bc] = b1;
        __syncthreads();
#pragma unroll
        for (int kk = 0; kk < 16; kk++) {
            float a[8], b[8];
            *(float4*)&a[0] = *(float4*)&As[kk][ty * 8];
            *(float4*)&a[4] = *(float4*)&As[kk][ty * 8 + 4];
            *(float4*)&b[0] = *(float4*)&Bs[kk][tx * 4];
            *(float4*)&b[4] = *(float4*)&Bs[kk][64 + tx * 4];
#pragma unroll
            for (int i = 0; i < 8; i++)
#pragma unroll
                for (int j = 0; j < 8; j++) acc[i][j] = fmaf(a[i], b[j], acc[i][j]);
        }
    }

#pragma unroll
    for (int i = 0; i < 8; i++) {
        int m = m0 + ty * 8 + i;
        int bidx = m >> 11, seq = m & (SEQ - 1);
#pragma unroll
        for (int jg = 0; jg < 2; jg++) {
            int n = n0 + jg * 64 + tx * 4;
            int which = n >> 10, rem = n & 1023;
            int h = rem >> 6, d = rem & 63;
            float* dst = (which == 0) ? qb : (which == 1) ? kb : vb;
            float4 v = make_float4(acc[i][jg * 4 + 0], acc[i][jg * 4 + 1],
                                   acc[i][jg * 4 + 2], acc[i][jg * 4 + 3]);
            *(float4*)&dst[((size_t)(bidx * HEADS + h) * SEQ + seq) * DHEAD + d] = v;
        }
    }
}

// ---------------- K3: per-head LayerNorm over DHEAD=64 (in place) ----------------
__global__ __launch_bounds__(256) void kvln_kernel(float* __restrict__ buf,
                                                   const float* __restrict__ g,
                                                   const float* __restrict__ b) {
    int row = blockIdx.x * 4 + (threadIdx.x >> 6);
    int lane = threadIdx.x & 63;
    float v = buf[(size_t)row * DHEAD + lane];
    float s = v, ss = v * v;
#pragma unroll
    for (int m = 32; m >= 1; m >>= 1) {
        s += __shfl_xor(s, m);
        ss += __shfl_xor(ss, m);
    }
    float mu = s * (1.f / DHEAD);
    float var = ss * (1.f / DHEAD) - mu * mu;
    float rsg = rsqrtf(var + LNEPS);
    buf[(size_t)row * DHEAD + lane] = (v - mu) * rsg * g[lane] + b[lane];
}

// ---------------- K4: flash attention, fp32, per (b,h) with 64-query blocks ----------------
__global__ __launch_bounds__(256) void attn_kernel(const float* __restrict__ qb,
                                                   const float* __restrict__ kb,
                                                   const float* __restrict__ vb,
                                                   float* __restrict__ ao) {
    __shared__ float Qs[64][68];  // [d][qrow]
    __shared__ float KP[64][68];  // phase 1: K transposed [d][krow]; phase 2: P [qrow][krow]
    __shared__ float Vs[64][68];  // [krow][d]
    const int bh = blockIdx.x;
    const int q0 = blockIdx.y * 64;
    const int t = threadIdx.x;
    const int ct = t & 15, rt = t >> 4;
    const int c0 = ct * 4, r0v = rt * 4;
    const float scale = 0.125f;  // DHEAD^-0.5
    const float* Qg = qb + ((size_t)bh * SEQ + q0) * DHEAD;
    const float* Kg = kb + (size_t)bh * SEQ * DHEAD;
    const float* Vg = vb + (size_t)bh * SEQ * DHEAD;

#pragma unroll
    for (int i = 0; i < 4; i++) {
        int idx = t + i * 256;
        int row = idx >> 4, d4 = (idx & 15) * 4;
        float4 v = *(const float4*)&Qg[row * DHEAD + d4];
        Qs[d4 + 0][row] = v.x;
        Qs[d4 + 1][row] = v.y;
        Qs[d4 + 2][row] = v.z;
        Qs[d4 + 3][row] = v.w;
    }

    float m_run[4], l_run[4], o[4][4];
#pragma unroll
    for (int i = 0; i < 4; i++) {
        m_run[i] = -INFINITY;
        l_run[i] = 0.f;
#pragma unroll
        for (int j = 0; j < 4; j++) o[i][j] = 0.f;
    }

    for (int kblk = 0; kblk < SEQ; kblk += 64) {
        float4 kv[4], vv[4];
#pragma unroll
        for (int i = 0; i < 4; i++) {
            int idx = t + i * 256;
            int row = idx >> 4, d4 = (idx & 15) * 4;
            kv[i] = *(const float4*)&Kg[(size_t)(kblk + row) * DHEAD + d4];
            vv[i] = *(const float4*)&Vg[(size_t)(kblk + row) * DHEAD + d4];
        }
        __syncthreads();  // prior iter's PV reads done (and Qs stores visible on iter 0)
#pragma unroll
        for (int i = 0; i < 4; i++) {
            int idx = t + i * 256;
            int row = idx >> 4, d4 = (idx & 15) * 4;
            KP[d4 + 0][row] = kv[i].x;
            KP[d4 + 1][row] = kv[i].y;
            KP[d4 + 2][row] = kv[i].z;
            KP[d4 + 3][row] = kv[i].w;
            *(float4*)&Vs[row][d4] = vv[i];
        }
        __syncthreads();

        float s[4][4];
#pragma unroll
        for (int i = 0; i < 4; i++)
#pragma unroll
            for (int j = 0; j < 4; j++) s[i][j] = 0.f;
#pragma unroll 8
        for (int d = 0; d < 64; d++) {
            float qa[4], ka[4];
            *(float4*)&qa[0] = *(float4*)&Qs[d][r0v];
            *(float4*)&ka[0] = *(float4*)&KP[d][c0];
#pragma unroll
            for (int i = 0; i < 4; i++)
#pragma unroll
                for (int j = 0; j < 4; j++) s[i][j] = fmaf(qa[i], ka[j], s[i][j]);
        }
#pragma unroll
        for (int i = 0; i < 4; i++)
#pragma unroll
            for (int j = 0; j < 4; j++) s[i][j] *= scale;

        // online softmax across the 16 lanes sharing this row group
#pragma unroll
        for (int i = 0; i < 4; i++) {
            float mx = fmaxf(fmaxf(s[i][0], s[i][1]), fmaxf(s[i][2], s[i][3]));
#pragma unroll
            for (int msk = 1; msk <= 8; msk <<= 1) mx = fmaxf(mx, __shfl_xor(mx, msk));
            float mn = fmaxf(m_run[i], mx);
            float sum = 0.f;
#pragma unroll
            for (int j = 0; j < 4; j++) {
                s[i][j] = expf(s[i][j] - mn);
                sum += s[i][j];
            }
#pragma unroll
            for (int msk = 1; msk <= 8; msk <<= 1) sum += __shfl_xor(sum, msk);
            float alpha = expf(m_run[i] - mn);
            l_run[i] = l_run[i] * alpha + sum;
            m_run[i] = mn;
#pragma unroll
            for (int j = 0; j < 4; j++) o[i][j] *= alpha;
        }

        __syncthreads();  // all S reads of KP done before P overwrite
#pragma unroll
        for (int i = 0; i < 4; i++)
            *(float4*)&KP[r0v + i][c0] = make_float4(s[i][0], s[i][1], s[i][2], s[i][3]);
        __syncthreads();

#pragma unroll 4
        for (int j4 = 0; j4 < 16; j4++) {
            float pa[4][4];
#pragma unroll
            for (int i = 0; i < 4; i++) *(float4*)&pa[i][0] = *(float4*)&KP[r0v + i][j4 * 4];
#pragma unroll
            for (int jj = 0; jj < 4; jj++) {
                float va[4];
                *(float4*)&va[0] = *(float4*)&Vs[j4 * 4 + jj][c0];
#pragma unroll
                for (int i = 0; i < 4; i++) {
                    o[i][0] = fmaf(pa[i][jj], va[0], o[i][0]);
                    o[i][1] = fmaf(pa[i][jj], va[1], o[i][1]);
                    o[i][2] = fmaf(pa[i][jj], va[2], o[i][2]);
                    o[i][3] = fmaf(pa[i][jj], va[3], o[i][3]);
                }
            }
        }
    }

    int b = bh >> 4, h = bh & 15;
#pragma unroll
    for (int i = 0; i < 4; i++) {
        float inv = 1.f / l_run[i];
        size_t off = ((size_t)(b * SEQ + q0 + r0v + i)) * NDIM + h * DHEAD + c0;
        *(float4*)&ao[off] = make_float4(o[i][0] * inv, o[i][1] * inv, o[i][2] * inv, o[i][3] * inv);
    }
}

// ---------------- K5: output GEMM + bias ----------------
__global__ __launch_bounds__(256) void out_gemm_kernel(const float* __restrict__ a,
                                                       const float* __restrict__ w,
                                                       const float* __restrict__ bias,
                                                       float* __restrict__ out) {
    __shared__ float As[16][132];
    __shared__ float Bs[16][132];
    const int t = threadIdx.x;
    const int m0 = blockIdx.x * 128;
    const int n0 = blockIdx.y * 128;
    const int tx = t & 15, ty = t >> 4;

    const int arow0 = t >> 2;
    const int arow1 = 64 + (t >> 2);
    const int ac = (t & 3) * 4;
    const int brow = t >> 5;
    const int bc = (t & 31) * 4;

    float acc[8][8];
#pragma unroll
    for (int i = 0; i < 8; i++)
#pragma unroll
        for (int j = 0; j < 8; j++) acc[i][j] = 0.f;

    for (int k0 = 0; k0 < NDIM; k0 += 16) {
        float4 a0 = *(const float4*)&a[(size_t)(m0 + arow0) * NDIM + k0 + ac];
        float4 a1 = *(const float4*)&a[(size_t)(m0 + arow1) * NDIM + k0 + ac];
        float4 b0 = *(const float4*)&w[(size_t)(k0 + brow) * NDIM + n0 + bc];
        float4 b1 = *(const float4*)&w[(size_t)(k0 + brow + 8) * NDIM + n0 + bc];
        __syncthreads();
        *(float4*)&Bs[brow][bc] = b0;
        *(float4*)&Bs[brow + 8][bc] = b1;
        As[ac + 0][arow0] = a0.x;
        As[ac + 1][arow0] = a0.y;
        As[ac + 2][arow0] = a0.z;
        As[ac + 3][arow0] = a0.w;
        As[ac + 0][arow1] = a1.x;
        As[ac + 1][arow1] = a1.y;
        As[ac + 2][arow1] = a1.z;
        As[ac + 3][arow1] = a1.w;
        __syncthreads();
#pragma unroll
        for (int kk = 0; kk < 16; kk++) {
            float av[8], bv[8];
            *(float4*)&av[0] = *(float4*)&As[kk][ty * 8];
            *(float4*)&av[4] = *(float4*)&As[kk][ty * 8 + 4];
            *(float4*)&bv[0] = *(float4*)&Bs[kk][tx * 4];
            *(float4*)&bv[4] = *(float4*)&Bs[kk][64 + tx * 4];
#pragma unroll
            for (int i = 0; i < 8; i++)
#pragma unroll
                for (int j = 0; j < 8; j++) acc[i][j] = fmaf(av[i], bv[j], acc[i][j]);
        }
    }

#pragma unroll
    for (int i = 0; i < 8; i++) {
        int m = m0 + ty * 8 + i;
#pragma unroll
        for (int jg = 0; jg < 2; jg++) {
            int n = n0 + jg * 64 + tx * 4;
            float4 bb = *(const float4*)&bias[n];
            float4 v = make_float4(acc[i][jg * 4 + 0] + bb.x, acc[i][jg * 4 + 1] + bb.y,
                                   acc[i][jg * 4 + 2] + bb.z, acc[i][jg * 4 + 3] + bb.w);
            *(float4*)&out[(size_t)m * NDIM + n] = v;
        }
    }
}

extern "C" void kernel_launch(void* const* d_in, const int* in_sizes, int n_in,
                              void* d_out, int out_size, void* d_ws, size_t ws_size,
                              hipStream_t stream) {
    const float* x       = (const float*)d_in[0];
    const float* norm_g  = (const float*)d_in[1];
    const float* norm_b  = (const float*)d_in[2];
    const float* w_qkv   = (const float*)d_in[3];
    const float* normk_g = (const float*)d_in[4];
    const float* normk_b = (const float*)d_in[5];
    const float* normv_g = (const float*)d_in[6];
    const float* normv_b = (const float*)d_in[7];
    const float* w_out   = (const float*)d_in[8];
    const float* b_out   = (const float*)d_in[9];
    float* out = (float*)d_out;

    const size_t TEN = (size_t)BATCH * HEADS * SEQ * DHEAD;  // 8388608 floats
    float* ws = (float*)d_ws;
    float* mu = ws;               // 8192
    float* rs = ws + NROWS;       // 8192
    float* qb = ws + 2 * NROWS;   // q  [B*H][SEQ][DHEAD]
    float* kb = qb + TEN;         // k
    float* vb = kb + TEN;         // v
    float* ao = vb + TEN;         // attention out in [B*SEQ][NDIM] layout

    ln_stats_kernel<<<NROWS, 256, 0, stream>>>(x, mu, rs);
    qkv_gemm_kernel<<<dim3(NROWS / 128, QKVN / 128), 256, 0, stream>>>(
        x, mu, rs, norm_g, norm_b, w_qkv, qb, kb, vb);
    kvln_kernel<<<BATCH * HEADS * SEQ / 4, 256, 0, stream>>>(kb, normk_g, normk_b);
    kvln_kernel<<<BATCH * HEADS * SEQ / 4, 256, 0, stream>>>(vb, normv_g, normv_b);
    attn_kernel<<<dim3(BATCH * HEADS, SEQ / 64), 256, 0, stream>>>(qb, kb, vb, ao);
    out_gemm_kernel<<<dim3(NROWS / 128, NDIM / 128), 256, 0, stream>>>(ao, w_out, b_out, out);
}

// Round 2
// 592.508 us; speedup vs baseline: 3.3418x; 3.3418x over previous
//
#include <hip/hip_runtime.h>
#include <math.h>

#define SEQ 2048
#define NDIM 1024
#define HEADS 16
#define DHEAD 64
#define NROWS 8192
#define QKVN 3072
#define LNEPS 1e-5f

typedef __attribute__((ext_vector_type(8))) short bf16x8;
typedef __attribute__((ext_vector_type(8))) unsigned short ushort8;
typedef __attribute__((ext_vector_type(4))) float f32x4;

__device__ __forceinline__ unsigned short f2bf(float f) {
    unsigned u = __float_as_uint(f);
    u += 0x7fff + ((u >> 16) & 1);   // RNE
    return (unsigned short)(u >> 16);
}

// ---------------- K1: fused LayerNorm(x) -> bf16 xn [8192][1024] ----------------
__global__ __launch_bounds__(256) void ln_norm_kernel(const float* __restrict__ x,
                                                      const float* __restrict__ g,
                                                      const float* __restrict__ b,
                                                      unsigned short* __restrict__ xn) {
    int row = blockIdx.x, t = threadIdx.x;
    float4 v = ((const float4*)(x + (size_t)row * NDIM))[t];
    float s = v.x + v.y + v.z + v.w;
    float ss = v.x * v.x + v.y * v.y + v.z * v.z + v.w * v.w;
#pragma unroll
    for (int m = 32; m >= 1; m >>= 1) { s += __shfl_xor(s, m); ss += __shfl_xor(ss, m); }
    __shared__ float r0[4], r1[4];
    if ((t & 63) == 0) { r0[t >> 6] = s; r1[t >> 6] = ss; }
    __syncthreads();
    float S = r0[0] + r0[1] + r0[2] + r0[3];
    float SS = r1[0] + r1[1] + r1[2] + r1[3];
    float mu = S * (1.f / NDIM);
    float rsg = rsqrtf(SS * (1.f / NDIM) - mu * mu + LNEPS);
    float4 gv = ((const float4*)g)[t];
    float4 bv = ((const float4*)b)[t];
    ushort4 o;
    o.x = f2bf((v.x - mu) * rsg * gv.x + bv.x);
    o.y = f2bf((v.y - mu) * rsg * gv.y + bv.y);
    o.z = f2bf((v.z - mu) * rsg * gv.z + bv.z);
    o.w = f2bf((v.w - mu) * rsg * gv.w + bv.w);
    ((ushort4*)(xn + (size_t)row * NDIM))[t] = o;
}

// ---------------- K2: transpose w_qkv [1024][3072] fp32 -> wT [3072][1024] bf16 ----------------
__global__ __launch_bounds__(256) void wtrans_kernel(const float* __restrict__ w,
                                                     unsigned short* __restrict__ wT) {
    __shared__ float Tt[32][36];
    int k0 = blockIdx.x * 32, n0 = blockIdx.y * 32;
    int t = threadIdx.x;
    int kr = t >> 3, nc = (t & 7) * 4;
    float4 v = *(const float4*)&w[(size_t)(k0 + kr) * QKVN + n0 + nc];
    Tt[kr][nc + 0] = v.x;
    Tt[kr][nc + 1] = v.y;
    Tt[kr][nc + 2] = v.z;
    Tt[kr][nc + 3] = v.w;
    __syncthreads();
    int nr = t >> 3, kc = (t & 7) * 4;
    ushort4 o;
    o.x = f2bf(Tt[kc + 0][nr]);
    o.y = f2bf(Tt[kc + 1][nr]);
    o.z = f2bf(Tt[kc + 2][nr]);
    o.w = f2bf(Tt[kc + 3][nr]);
    *(ushort4*)&wT[(size_t)(n0 + nr) * NDIM + k0 + kc] = o;
}

// ---------------- K3: bf16 MFMA QKV GEMM, epilogue fuses K-LN, V-LN + V-transpose ----------------
__global__ __launch_bounds__(256) void qkv_gemm_mfma(
    const unsigned short* __restrict__ xn, const unsigned short* __restrict__ wT,
    const float* __restrict__ gk, const float* __restrict__ bk,
    const float* __restrict__ gv, const float* __restrict__ bv,
    unsigned short* __restrict__ qb, unsigned short* __restrict__ kb,
    unsigned short* __restrict__ vt) {
    __shared__ short As[128][40];   // [m][k] pad 32->40
    __shared__ short Bs[128][40];   // [n][k]
    const int t = threadIdx.x;
    const int lane = t & 63, wid = t >> 6;
    const int wr = wid >> 1, wc = wid & 1;
    const int l15 = lane & 15, l4 = lane >> 4;
    const int m0 = blockIdx.x * 128, n0 = blockIdx.y * 128;
    const int ar = t >> 1, as = (t & 1) * 16;

    f32x4 acc[4][4];
#pragma unroll
    for (int i = 0; i < 4; i++)
#pragma unroll
        for (int j = 0; j < 4; j++) acc[i][j] = (f32x4){0.f, 0.f, 0.f, 0.f};

    const unsigned short* ag = xn + (size_t)(m0 + ar) * NDIM + as;
    const unsigned short* bg = wT + (size_t)(n0 + ar) * NDIM + as;

    for (int k0 = 0; k0 < NDIM; k0 += 32) {
        ushort8 a0 = *(const ushort8*)(ag + k0);
        ushort8 a1 = *(const ushort8*)(ag + k0 + 8);
        ushort8 b0 = *(const ushort8*)(bg + k0);
        ushort8 b1 = *(const ushort8*)(bg + k0 + 8);
        __syncthreads();
        *(ushort8*)&As[ar][as] = a0;
        *(ushort8*)&As[ar][as + 8] = a1;
        *(ushort8*)&Bs[ar][as] = b0;
        *(ushort8*)&Bs[ar][as + 8] = b1;
        __syncthreads();
        bf16x8 af[4];
#pragma unroll
        for (int mi = 0; mi < 4; mi++)
            af[mi] = *(const bf16x8*)&As[64 * wr + 16 * mi + l15][8 * l4];
#pragma unroll
        for (int ni = 0; ni < 4; ni++) {
            bf16x8 bfr = *(const bf16x8*)&Bs[64 * wc + 16 * ni + l15][8 * l4];
#pragma unroll
            for (int mi = 0; mi < 4; mi++)
                acc[mi][ni] = __builtin_amdgcn_mfma_f32_16x16x32_bf16(af[mi], bfr, acc[mi][ni], 0, 0, 0);
        }
    }

    const int nblk = n0 + 64 * wc;
    const int which = nblk >> 10;
    const int h = (nblk >> 6) & 15;
    const int mb = m0 + 64 * wr;

    if (which == 0) {
#pragma unroll
        for (int mi = 0; mi < 4; mi++)
#pragma unroll
            for (int r = 0; r < 4; r++) {
                int m = mb + 16 * mi + 4 * l4 + r;
                int bb = m >> 11, s = m & (SEQ - 1);
                size_t base = ((size_t)(bb * HEADS + h) * SEQ + s) * DHEAD;
#pragma unroll
                for (int ni = 0; ni < 4; ni++)
                    qb[base + 16 * ni + l15] = f2bf(acc[mi][ni][r]);
            }
    } else if (which == 1) {
        float gw[4], bw[4];
#pragma unroll
        for (int ni = 0; ni < 4; ni++) { gw[ni] = gk[16 * ni + l15]; bw[ni] = bk[16 * ni + l15]; }
#pragma unroll
        for (int mi = 0; mi < 4; mi++)
#pragma unroll
            for (int r = 0; r < 4; r++) {
                float sum = 0.f, ssum = 0.f;
#pragma unroll
                for (int ni = 0; ni < 4; ni++) { float v = acc[mi][ni][r]; sum += v; ssum += v * v; }
#pragma unroll
                for (int msk = 1; msk <= 8; msk <<= 1) { sum += __shfl_xor(sum, msk); ssum += __shfl_xor(ssum, msk); }
                float mu = sum * (1.f / DHEAD);
                float rsg = rsqrtf(ssum * (1.f / DHEAD) - mu * mu + LNEPS);
                int m = mb + 16 * mi + 4 * l4 + r;
                int bb = m >> 11, s = m & (SEQ - 1);
                size_t base = ((size_t)(bb * HEADS + h) * SEQ + s) * DHEAD;
#pragma unroll
                for (int ni = 0; ni < 4; ni++)
                    kb[base + 16 * ni + l15] = f2bf((acc[mi][ni][r] - mu) * rsg * gw[ni] + bw[ni]);
            }
    } else {
        float gw[4], bw[4];
#pragma unroll
        for (int ni = 0; ni < 4; ni++) { gw[ni] = gv[16 * ni + l15]; bw[ni] = bv[16 * ni + l15]; }
#pragma unroll
        for (int mi = 0; mi < 4; mi++) {
            float mu4[4], rs4[4];
#pragma unroll
            for (int r = 0; r < 4; r++) {
                float sum = 0.f, ssum = 0.f;
#pragma unroll
                for (int ni = 0; ni < 4; ni++) { float v = acc[mi][ni][r]; sum += v; ssum += v * v; }
#pragma unroll
                for (int msk = 1; msk <= 8; msk <<= 1) { sum += __shfl_xor(sum, msk); ssum += __shfl_xor(ssum, msk); }
                float mu = sum * (1.f / DHEAD);
                mu4[r] = mu;
                rs4[r] = rsqrtf(ssum * (1.f / DHEAD) - mu * mu + LNEPS);
            }
            int m = mb + 16 * mi + 4 * l4;
            int bb = m >> 11, s = m & (SEQ - 1);
#pragma unroll
            for (int ni = 0; ni < 4; ni++) {
                ushort4 o;
                o.x = f2bf((acc[mi][ni][0] - mu4[0]) * rs4[0] * gw[ni] + bw[ni]);
                o.y = f2bf((acc[mi][ni][1] - mu4[1]) * rs4[1] * gw[ni] + bw[ni]);
                o.z = f2bf((acc[mi][ni][2] - mu4[2]) * rs4[2] * gw[ni] + bw[ni]);
                o.w = f2bf((acc[mi][ni][3] - mu4[3]) * rs4[3] * gw[ni] + bw[ni]);
                *(ushort4*)&vt[((size_t)(bb * HEADS + h) * DHEAD + 16 * ni + l15) * SEQ + s] = o;
            }
        }
    }
}

// ---------------- K4: bf16 MFMA flash attention ----------------
__global__ __launch_bounds__(256) void attn_mfma(
    const unsigned short* __restrict__ qb, const unsigned short* __restrict__ kb,
    const unsigned short* __restrict__ vt, float* __restrict__ ao) {
    __shared__ short QP[128][72];  // Q staging, then wave-private P
    __shared__ short Ks[64][72];   // [kv][d]
    __shared__ short Vs[64][72];   // [d][kv]
    const int t = threadIdx.x;
    const int lane = t & 63, wid = t >> 6;
    const int l15 = lane & 15, l4 = lane >> 4;
    const int bh = blockIdx.y;
    const int q0 = blockIdx.x * 128;
    const unsigned short* Qg = qb + ((size_t)bh * SEQ + q0) * DHEAD;
    const unsigned short* Kg = kb + (size_t)bh * SEQ * DHEAD;
    const unsigned short* Vg = vt + (size_t)bh * DHEAD * SEQ;

#pragma unroll
    for (int i = 0; i < 4; i++) {
        int u = t + 256 * i, row = u >> 3, seg = (u & 7) * 8;
        *(ushort8*)&QP[row][seg] = *(const ushort8*)&Qg[(size_t)row * DHEAD + seg];
    }
    __syncthreads();
    bf16x8 qf[2][2];
#pragma unroll
    for (int mi = 0; mi < 2; mi++)
#pragma unroll
        for (int kk = 0; kk < 2; kk++)
            qf[mi][kk] = *(const bf16x8*)&QP[32 * wid + 16 * mi + l15][32 * kk + 8 * l4];

    f32x4 po[2][4];
    float m_run[2][4], l_run[2][4];
#pragma unroll
    for (int mi = 0; mi < 2; mi++) {
#pragma unroll
        for (int r = 0; r < 4; r++) { m_run[mi][r] = -INFINITY; l_run[mi][r] = 0.f; }
#pragma unroll
        for (int di = 0; di < 4; di++) po[mi][di] = (f32x4){0.f, 0.f, 0.f, 0.f};
    }

    const int row = t >> 3, seg = (t & 7) * 8;
    const int row1 = (t + 256) >> 3, seg1 = ((t + 256) & 7) * 8;

    for (int kv0 = 0; kv0 < SEQ; kv0 += 64) {
        ushort8 kr0 = *(const ushort8*)&Kg[(size_t)(kv0 + row) * DHEAD + seg];
        ushort8 vr0 = *(const ushort8*)&Vg[(size_t)row * SEQ + kv0 + seg];
        ushort8 kr1 = *(const ushort8*)&Kg[(size_t)(kv0 + row1) * DHEAD + seg1];
        ushort8 vr1 = *(const ushort8*)&Vg[(size_t)row1 * SEQ + kv0 + seg1];
        __syncthreads();
        *(ushort8*)&Ks[row][seg] = kr0;
        *(ushort8*)&Vs[row][seg] = vr0;
        *(ushort8*)&Ks[row1][seg1] = kr1;
        *(ushort8*)&Vs[row1][seg1] = vr1;
        __syncthreads();

        f32x4 sc[2][4];
#pragma unroll
        for (int mi = 0; mi < 2; mi++)
#pragma unroll
            for (int ni = 0; ni < 4; ni++) sc[mi][ni] = (f32x4){0.f, 0.f, 0.f, 0.f};
#pragma unroll
        for (int kk = 0; kk < 2; kk++)
#pragma unroll
            for (int ni = 0; ni < 4; ni++) {
                bf16x8 kf = *(const bf16x8*)&Ks[16 * ni + l15][32 * kk + 8 * l4];
#pragma unroll
                for (int mi = 0; mi < 2; mi++)
                    sc[mi][ni] = __builtin_amdgcn_mfma_f32_16x16x32_bf16(qf[mi][kk], kf, sc[mi][ni], 0, 0, 0);
            }

#pragma unroll
        for (int mi = 0; mi < 2; mi++)
#pragma unroll
            for (int r = 0; r < 4; r++) {
                float s0 = sc[mi][0][r] * 0.125f;
                float s1 = sc[mi][1][r] * 0.125f;
                float s2 = sc[mi][2][r] * 0.125f;
                float s3 = sc[mi][3][r] * 0.125f;
                float mx = fmaxf(fmaxf(s0, s1), fmaxf(s2, s3));
#pragma unroll
                for (int msk = 1; msk <= 8; msk <<= 1) mx = fmaxf(mx, __shfl_xor(mx, msk));
                float mn = fmaxf(m_run[mi][r], mx);
                float p0 = __expf(s0 - mn), p1 = __expf(s1 - mn);
                float p2 = __expf(s2 - mn), p3 = __expf(s3 - mn);
                float sum = p0 + p1 + p2 + p3;
#pragma unroll
                for (int msk = 1; msk <= 8; msk <<= 1) sum += __shfl_xor(sum, msk);
                float alpha = __expf(m_run[mi][r] - mn);
                m_run[mi][r] = mn;
                l_run[mi][r] = l_run[mi][r] * alpha + sum;
#pragma unroll
                for (int di = 0; di < 4; di++) po[mi][di][r] *= alpha;
                short* pr = &QP[32 * wid + 16 * mi + 4 * l4 + r][l15];
                pr[0]  = (short)f2bf(p0);
                pr[16] = (short)f2bf(p1);
                pr[32] = (short)f2bf(p2);
                pr[48] = (short)f2bf(p3);
            }

#pragma unroll
        for (int kk = 0; kk < 2; kk++) {
            bf16x8 pa[2];
#pragma unroll
            for (int mi = 0; mi < 2; mi++)
                pa[mi] = *(const bf16x8*)&QP[32 * wid + 16 * mi + l15][32 * kk + 8 * l4];
#pragma unroll
            for (int di = 0; di < 4; di++) {
                bf16x8 vf = *(const bf16x8*)&Vs[16 * di + l15][32 * kk + 8 * l4];
#pragma unroll
                for (int mi = 0; mi < 2; mi++)
                    po[mi][di] = __builtin_amdgcn_mfma_f32_16x16x32_bf16(pa[mi], vf, po[mi][di], 0, 0, 0);
            }
        }
    }

    const int bb = bh >> 4, h = bh & 15;
#pragma unroll
    for (int mi = 0; mi < 2; mi++)
#pragma unroll
        for (int r = 0; r < 4; r++) {
            float inv = 1.f / l_run[mi][r];
            int ml = 32 * wid + 16 * mi + 4 * l4 + r;
            size_t base = ((size_t)(bb * SEQ + q0 + ml)) * NDIM + h * DHEAD;
#pragma unroll
            for (int di = 0; di < 4; di++)
                ao[base + 16 * di + l15] = po[mi][di][r] * inv;
        }
}

// ---------------- K5: output GEMM + bias (fp32, unchanged) ----------------
__global__ __launch_bounds__(256) void out_gemm_kernel(const float* __restrict__ a,
                                                       const float* __restrict__ w,
                                                       const float* __restrict__ bias,
                                                       float* __restrict__ out) {
    __shared__ float As[16][132];
    __shared__ float Bs[16][132];
    const int t = threadIdx.x;
    const int m0 = blockIdx.x * 128;
    const int n0 = blockIdx.y * 128;
    const int tx = t & 15, ty = t >> 4;

    const int arow0 = t >> 2;
    const int arow1 = 64 + (t >> 2);
    const int ac = (t & 3) * 4;
    const int brow = t >> 5;
    const int bc = (t & 31) * 4;

    float acc[8][8];
#pragma unroll
    for (int i = 0; i < 8; i++)
#pragma unroll
        for (int j = 0; j < 8; j++) acc[i][j] = 0.f;

    for (int k0 = 0; k0 < NDIM; k0 += 16) {
        float4 a0 = *(const float4*)&a[(size_t)(m0 + arow0) * NDIM + k0 + ac];
        float4 a1 = *(const float4*)&a[(size_t)(m0 + arow1) * NDIM + k0 + ac];
        float4 b0 = *(const float4*)&w[(size_t)(k0 + brow) * NDIM + n0 + bc];
        float4 b1 = *(const float4*)&w[(size_t)(k0 + brow + 8) * NDIM + n0 + bc];
        __syncthreads();
        *(float4*)&Bs[brow][bc] = b0;
        *(float4*)&Bs[brow + 8][bc] = b1;
        As[ac + 0][arow0] = a0.x;
        As[ac + 1][arow0] = a0.y;
        As[ac + 2][arow0] = a0.z;
        As[ac + 3][arow0] = a0.w;
        As[ac + 0][arow1] = a1.x;
        As[ac + 1][arow1] = a1.y;
        As[ac + 2][arow1] = a1.z;
        As[ac + 3][arow1] = a1.w;
        __syncthreads();
#pragma unroll
        for (int kk = 0; kk < 16; kk++) {
            float av[8], bv[8];
            *(float4*)&av[0] = *(float4*)&As[kk][ty * 8];
            *(float4*)&av[4] = *(float4*)&As[kk][ty * 8 + 4];
            *(float4*)&bv[0] = *(float4*)&Bs[kk][tx * 4];
            *(float4*)&bv[4] = *(float4*)&Bs[kk][64 + tx * 4];
#pragma unroll
            for (int i = 0; i < 8; i++)
#pragma unroll
                for (int j = 0; j < 8; j++) acc[i][j] = fmaf(av[i], bv[j], acc[i][j]);
        }
    }

#pragma unroll
    for (int i = 0; i < 8; i++) {
        int m = m0 + ty * 8 + i;
#pragma unroll
        for (int jg = 0; jg < 2; jg++) {
            int n = n0 + jg * 64 + tx * 4;
            float4 bb = *(const float4*)&bias[n];
            float4 v = make_float4(acc[i][jg * 4 + 0] + bb.x, acc[i][jg * 4 + 1] + bb.y,
                                   acc[i][jg * 4 + 2] + bb.z, acc[i][jg * 4 + 3] + bb.w);
            *(float4*)&out[(size_t)m * NDIM + n] = v;
        }
    }
}

extern "C" void kernel_launch(void* const* d_in, const int* in_sizes, int n_in,
                              void* d_out, int out_size, void* d_ws, size_t ws_size,
                              hipStream_t stream) {
    const float* x       = (const float*)d_in[0];
    const float* norm_g  = (const float*)d_in[1];
    const float* norm_b  = (const float*)d_in[2];
    const float* w_qkv   = (const float*)d_in[3];
    const float* normk_g = (const float*)d_in[4];
    const float* normk_b = (const float*)d_in[5];
    const float* normv_g = (const float*)d_in[6];
    const float* normv_b = (const float*)d_in[7];
    const float* w_out   = (const float*)d_in[8];
    const float* b_out   = (const float*)d_in[9];
    float* out = (float*)d_out;

    char* p = (char*)d_ws;
    unsigned short* xn = (unsigned short*)p; p += (size_t)NROWS * NDIM * 2;
    unsigned short* wT = (unsigned short*)p; p += (size_t)QKVN * NDIM * 2;
    unsigned short* qb = (unsigned short*)p; p += (size_t)NROWS * NDIM * 2;
    unsigned short* kb = (unsigned short*)p; p += (size_t)NROWS * NDIM * 2;
    unsigned short* vt = (unsigned short*)p; p += (size_t)NROWS * NDIM * 2;
    float* ao = (float*)p;

    ln_norm_kernel<<<NROWS, 256, 0, stream>>>(x, norm_g, norm_b, xn);
    wtrans_kernel<<<dim3(NDIM / 32, QKVN / 32), 256, 0, stream>>>(w_qkv, wT);
    qkv_gemm_mfma<<<dim3(NROWS / 128, QKVN / 128), 256, 0, stream>>>(
        xn, wT, normk_g, normk_b, normv_g, normv_b, qb, kb, vt);
    attn_mfma<<<dim3(SEQ / 128, 64), 256, 0, stream>>>(qb, kb, vt, ao);
    out_gemm_kernel<<<dim3(NROWS / 128, NDIM / 128), 256, 0, stream>>>(ao, w_out, b_out, out);
}

// Round 3
// 409.444 us; speedup vs baseline: 4.8360x; 1.4471x over previous
//
#include <hip/hip_runtime.h>
#include <math.h>

#define SEQ 2048
#define NDIM 1024
#define HEADS 16
#define DHEAD 64
#define NROWS 8192
#define QKVN 3072
#define LNEPS 1e-5f
// fold attention scale AND log2(e) into Q so scores are in log2-domain
#define QSCALE (0.125f * 1.44269504088896341f)

typedef __attribute__((ext_vector_type(8))) short bf16x8;
typedef __attribute__((ext_vector_type(8))) unsigned short ushort8;
typedef __attribute__((ext_vector_type(4))) float f32x4;

__device__ __forceinline__ unsigned short f2bf(float f) {
    unsigned u = __float_as_uint(f);
    u += 0x7fff + ((u >> 16) & 1);   // RNE
    return (unsigned short)(u >> 16);
}

// ---------------- K1: fused LayerNorm(x) -> bf16 xn [8192][1024] ----------------
__global__ __launch_bounds__(256) void ln_norm_kernel(const float* __restrict__ x,
                                                      const float* __restrict__ g,
                                                      const float* __restrict__ b,
                                                      unsigned short* __restrict__ xn) {
    int row = blockIdx.x, t = threadIdx.x;
    float4 v = ((const float4*)(x + (size_t)row * NDIM))[t];
    float s = v.x + v.y + v.z + v.w;
    float ss = v.x * v.x + v.y * v.y + v.z * v.z + v.w * v.w;
#pragma unroll
    for (int m = 32; m >= 1; m >>= 1) { s += __shfl_xor(s, m); ss += __shfl_xor(ss, m); }
    __shared__ float r0[4], r1[4];
    if ((t & 63) == 0) { r0[t >> 6] = s; r1[t >> 6] = ss; }
    __syncthreads();
    float S = r0[0] + r0[1] + r0[2] + r0[3];
    float SS = r1[0] + r1[1] + r1[2] + r1[3];
    float mu = S * (1.f / NDIM);
    float rsg = rsqrtf(SS * (1.f / NDIM) - mu * mu + LNEPS);
    float4 gv = ((const float4*)g)[t];
    float4 bv = ((const float4*)b)[t];
    ushort4 o;
    o.x = f2bf((v.x - mu) * rsg * gv.x + bv.x);
    o.y = f2bf((v.y - mu) * rsg * gv.y + bv.y);
    o.z = f2bf((v.z - mu) * rsg * gv.z + bv.z);
    o.w = f2bf((v.w - mu) * rsg * gv.w + bv.w);
    ((ushort4*)(xn + (size_t)row * NDIM))[t] = o;
}

// ---------------- K2: transpose w [1024][N] fp32 -> wT [N][1024] bf16 ----------------
__global__ __launch_bounds__(256) void wtrans_kernel(const float* __restrict__ w,
                                                     unsigned short* __restrict__ wT,
                                                     int N) {
    __shared__ float Tt[32][36];
    int k0 = blockIdx.x * 32, n0 = blockIdx.y * 32;
    int t = threadIdx.x;
    int kr = t >> 3, nc = (t & 7) * 4;
    float4 v = *(const float4*)&w[(size_t)(k0 + kr) * N + n0 + nc];
    Tt[kr][nc + 0] = v.x;
    Tt[kr][nc + 1] = v.y;
    Tt[kr][nc + 2] = v.z;
    Tt[kr][nc + 3] = v.w;
    __syncthreads();
    int nr = t >> 3, kc = (t & 7) * 4;
    ushort4 o;
    o.x = f2bf(Tt[kc + 0][nr]);
    o.y = f2bf(Tt[kc + 1][nr]);
    o.z = f2bf(Tt[kc + 2][nr]);
    o.w = f2bf(Tt[kc + 3][nr]);
    *(ushort4*)&wT[(size_t)(n0 + nr) * NDIM + k0 + kc] = o;
}

// ---------------- K3: bf16 MFMA QKV GEMM, epilogue fuses Q-scale, K-LN, V-LN + V-transpose ----------------
__global__ __launch_bounds__(256) void qkv_gemm_mfma(
    const unsigned short* __restrict__ xn, const unsigned short* __restrict__ wT,
    const float* __restrict__ gk, const float* __restrict__ bk,
    const float* __restrict__ gv, const float* __restrict__ bv,
    unsigned short* __restrict__ qb, unsigned short* __restrict__ kb,
    unsigned short* __restrict__ vt) {
    __shared__ short As[128][40];   // [m][k] pad 32->40
    __shared__ short Bs[128][40];   // [n][k]
    const int t = threadIdx.x;
    const int lane = t & 63, wid = t >> 6;
    const int wr = wid >> 1, wc = wid & 1;
    const int l15 = lane & 15, l4 = lane >> 4;
    const int m0 = blockIdx.x * 128, n0 = blockIdx.y * 128;
    const int ar = t >> 1, as = (t & 1) * 16;

    f32x4 acc[4][4];
#pragma unroll
    for (int i = 0; i < 4; i++)
#pragma unroll
        for (int j = 0; j < 4; j++) acc[i][j] = (f32x4){0.f, 0.f, 0.f, 0.f};

    const unsigned short* ag = xn + (size_t)(m0 + ar) * NDIM + as;
    const unsigned short* bg = wT + (size_t)(n0 + ar) * NDIM + as;

    for (int k0 = 0; k0 < NDIM; k0 += 32) {
        ushort8 a0 = *(const ushort8*)(ag + k0);
        ushort8 a1 = *(const ushort8*)(ag + k0 + 8);
        ushort8 b0 = *(const ushort8*)(bg + k0);
        ushort8 b1 = *(const ushort8*)(bg + k0 + 8);
        __syncthreads();
        *(ushort8*)&As[ar][as] = a0;
        *(ushort8*)&As[ar][as + 8] = a1;
        *(ushort8*)&Bs[ar][as] = b0;
        *(ushort8*)&Bs[ar][as + 8] = b1;
        __syncthreads();
        bf16x8 af[4];
#pragma unroll
        for (int mi = 0; mi < 4; mi++)
            af[mi] = *(const bf16x8*)&As[64 * wr + 16 * mi + l15][8 * l4];
#pragma unroll
        for (int ni = 0; ni < 4; ni++) {
            bf16x8 bfr = *(const bf16x8*)&Bs[64 * wc + 16 * ni + l15][8 * l4];
#pragma unroll
            for (int mi = 0; mi < 4; mi++)
                acc[mi][ni] = __builtin_amdgcn_mfma_f32_16x16x32_bf16(af[mi], bfr, acc[mi][ni], 0, 0, 0);
        }
    }

    const int nblk = n0 + 64 * wc;
    const int which = nblk >> 10;
    const int h = (nblk >> 6) & 15;
    const int mb = m0 + 64 * wr;

    if (which == 0) {  // Q: scale folded in
#pragma unroll
        for (int mi = 0; mi < 4; mi++)
#pragma unroll
            for (int r = 0; r < 4; r++) {
                int m = mb + 16 * mi + 4 * l4 + r;
                int bb = m >> 11, s = m & (SEQ - 1);
                size_t base = ((size_t)(bb * HEADS + h) * SEQ + s) * DHEAD;
#pragma unroll
                for (int ni = 0; ni < 4; ni++)
                    qb[base + 16 * ni + l15] = f2bf(acc[mi][ni][r] * QSCALE);
            }
    } else if (which == 1) {  // K: per-row LN over d
        float gw[4], bw[4];
#pragma unroll
        for (int ni = 0; ni < 4; ni++) { gw[ni] = gk[16 * ni + l15]; bw[ni] = bk[16 * ni + l15]; }
#pragma unroll
        for (int mi = 0; mi < 4; mi++)
#pragma unroll
            for (int r = 0; r < 4; r++) {
                float sum = 0.f, ssum = 0.f;
#pragma unroll
                for (int ni = 0; ni < 4; ni++) { float v = acc[mi][ni][r]; sum += v; ssum += v * v; }
#pragma unroll
                for (int msk = 1; msk <= 8; msk <<= 1) { sum += __shfl_xor(sum, msk); ssum += __shfl_xor(ssum, msk); }
                float mu = sum * (1.f / DHEAD);
                float rsg = rsqrtf(ssum * (1.f / DHEAD) - mu * mu + LNEPS);
                int m = mb + 16 * mi + 4 * l4 + r;
                int bb = m >> 11, s = m & (SEQ - 1);
                size_t base = ((size_t)(bb * HEADS + h) * SEQ + s) * DHEAD;
#pragma unroll
                for (int ni = 0; ni < 4; ni++)
                    kb[base + 16 * ni + l15] = f2bf((acc[mi][ni][r] - mu) * rsg * gw[ni] + bw[ni]);
            }
    } else {  // V: per-row LN then transposed store vt[bh][d][s]
        float gw[4], bw[4];
#pragma unroll
        for (int ni = 0; ni < 4; ni++) { gw[ni] = gv[16 * ni + l15]; bw[ni] = bv[16 * ni + l15]; }
#pragma unroll
        for (int mi = 0; mi < 4; mi++) {
            float mu4[4], rs4[4];
#pragma unroll
            for (int r = 0; r < 4; r++) {
                float sum = 0.f, ssum = 0.f;
#pragma unroll
                for (int ni = 0; ni < 4; ni++) { float v = acc[mi][ni][r]; sum += v; ssum += v * v; }
#pragma unroll
                for (int msk = 1; msk <= 8; msk <<= 1) { sum += __shfl_xor(sum, msk); ssum += __shfl_xor(ssum, msk); }
                float mu = sum * (1.f / DHEAD);
                mu4[r] = mu;
                rs4[r] = rsqrtf(ssum * (1.f / DHEAD) - mu * mu + LNEPS);
            }
            int m = mb + 16 * mi + 4 * l4;
            int bb = m >> 11, s = m & (SEQ - 1);
#pragma unroll
            for (int ni = 0; ni < 4; ni++) {
                ushort4 o;
                o.x = f2bf((acc[mi][ni][0] - mu4[0]) * rs4[0] * gw[ni] + bw[ni]);
                o.y = f2bf((acc[mi][ni][1] - mu4[1]) * rs4[1] * gw[ni] + bw[ni]);
                o.z = f2bf((acc[mi][ni][2] - mu4[2]) * rs4[2] * gw[ni] + bw[ni]);
                o.w = f2bf((acc[mi][ni][3] - mu4[3]) * rs4[3] * gw[ni] + bw[ni]);
                *(ushort4*)&vt[((size_t)(bb * HEADS + h) * DHEAD + 16 * ni + l15) * SEQ + s] = o;
            }
        }
    }
}

// ---------------- K4: bf16 MFMA flash attention (log2-domain, defer-max) ----------------
__global__ __launch_bounds__(256) void attn_mfma(
    const unsigned short* __restrict__ qb, const unsigned short* __restrict__ kb,
    const unsigned short* __restrict__ vt, unsigned short* __restrict__ ao) {
    __shared__ short QP[128][72];  // Q staging, then wave-private P
    __shared__ short Ks[64][72];   // [kv][d]
    __shared__ short Vs[64][72];   // [d][kv]
    const int t = threadIdx.x;
    const int lane = t & 63, wid = t >> 6;
    const int l15 = lane & 15, l4 = lane >> 4;
    // bijective XCD-chunked swizzle: 1024 blocks -> 8 chunks of 128 (8 bh per XCD)
    const int flat = blockIdx.x + (int)gridDim.x * blockIdx.y;
    const int swz = (flat & 7) * 128 + (flat >> 3);
    const int bh = swz >> 4;
    const int q0 = (swz & 15) * 128;
    const unsigned short* Qg = qb + ((size_t)bh * SEQ + q0) * DHEAD;
    const unsigned short* Kg = kb + (size_t)bh * SEQ * DHEAD;
    const unsigned short* Vg = vt + (size_t)bh * DHEAD * SEQ;

#pragma unroll
    for (int i = 0; i < 4; i++) {
        int u = t + 256 * i, row = u >> 3, seg = (u & 7) * 8;
        *(ushort8*)&QP[row][seg] = *(const ushort8*)&Qg[(size_t)row * DHEAD + seg];
    }
    __syncthreads();
    bf16x8 qf[2][2];
#pragma unroll
    for (int mi = 0; mi < 2; mi++)
#pragma unroll
        for (int kk = 0; kk < 2; kk++)
            qf[mi][kk] = *(const bf16x8*)&QP[32 * wid + 16 * mi + l15][32 * kk + 8 * l4];

    f32x4 po[2][4];
    float m_run[2][4], l_run[2][4];
#pragma unroll
    for (int mi = 0; mi < 2; mi++) {
#pragma unroll
        for (int r = 0; r < 4; r++) { m_run[mi][r] = -INFINITY; l_run[mi][r] = 0.f; }
#pragma unroll
        for (int di = 0; di < 4; di++) po[mi][di] = (f32x4){0.f, 0.f, 0.f, 0.f};
    }

    const int row = t >> 3, seg = (t & 7) * 8;
    const int row1 = (t + 256) >> 3, seg1 = ((t + 256) & 7) * 8;

    for (int kv0 = 0; kv0 < SEQ; kv0 += 64) {
        ushort8 kr0 = *(const ushort8*)&Kg[(size_t)(kv0 + row) * DHEAD + seg];
        ushort8 vr0 = *(const ushort8*)&Vg[(size_t)row * SEQ + kv0 + seg];
        ushort8 kr1 = *(const ushort8*)&Kg[(size_t)(kv0 + row1) * DHEAD + seg1];
        ushort8 vr1 = *(const ushort8*)&Vg[(size_t)row1 * SEQ + kv0 + seg1];
        __syncthreads();
        *(ushort8*)&Ks[row][seg] = kr0;
        *(ushort8*)&Vs[row][seg] = vr0;
        *(ushort8*)&Ks[row1][seg1] = kr1;
        *(ushort8*)&Vs[row1][seg1] = vr1;
        __syncthreads();

        f32x4 sc[2][4];
#pragma unroll
        for (int mi = 0; mi < 2; mi++)
#pragma unroll
            for (int ni = 0; ni < 4; ni++) sc[mi][ni] = (f32x4){0.f, 0.f, 0.f, 0.f};
#pragma unroll
        for (int kk = 0; kk < 2; kk++)
#pragma unroll
            for (int ni = 0; ni < 4; ni++) {
                bf16x8 kf = *(const bf16x8*)&Ks[16 * ni + l15][32 * kk + 8 * l4];
#pragma unroll
                for (int mi = 0; mi < 2; mi++)
                    sc[mi][ni] = __builtin_amdgcn_mfma_f32_16x16x32_bf16(qf[mi][kk], kf, sc[mi][ni], 0, 0, 0);
            }

        // scores already in log2 domain (scale*log2e folded into Q)
        float mxv[2][4];
        int myc = 1;
#pragma unroll
        for (int mi = 0; mi < 2; mi++)
#pragma unroll
            for (int r = 0; r < 4; r++) {
                float mx = fmaxf(fmaxf(sc[mi][0][r], sc[mi][1][r]),
                                 fmaxf(sc[mi][2][r], sc[mi][3][r]));
#pragma unroll
                for (int msk = 1; msk <= 8; msk <<= 1) mx = fmaxf(mx, __shfl_xor(mx, msk));
                mxv[mi][r] = mx;
                myc &= (mx <= m_run[mi][r] + 8.f) ? 1 : 0;
            }
        if (!__all(myc)) {  // rescale path (rare after first tile)
#pragma unroll
            for (int mi = 0; mi < 2; mi++)
#pragma unroll
                for (int r = 0; r < 4; r++) {
                    float mn = fmaxf(m_run[mi][r], mxv[mi][r]);
                    float alpha = exp2f(m_run[mi][r] - mn);
                    m_run[mi][r] = mn;
                    l_run[mi][r] *= alpha;
#pragma unroll
                    for (int di = 0; di < 4; di++) po[mi][di][r] *= alpha;
                }
        }
#pragma unroll
        for (int mi = 0; mi < 2; mi++)
#pragma unroll
            for (int r = 0; r < 4; r++) {
                float m = m_run[mi][r];
                float p0 = exp2f(sc[mi][0][r] - m), p1 = exp2f(sc[mi][1][r] - m);
                float p2 = exp2f(sc[mi][2][r] - m), p3 = exp2f(sc[mi][3][r] - m);
                float sum = p0 + p1 + p2 + p3;
#pragma unroll
                for (int msk = 1; msk <= 8; msk <<= 1) sum += __shfl_xor(sum, msk);
                l_run[mi][r] += sum;
                short* pr = &QP[32 * wid + 16 * mi + 4 * l4 + r][l15];
                pr[0]  = (short)f2bf(p0);
                pr[16] = (short)f2bf(p1);
                pr[32] = (short)f2bf(p2);
                pr[48] = (short)f2bf(p3);
            }

#pragma unroll
        for (int kk = 0; kk < 2; kk++) {
            bf16x8 pa[2];
#pragma unroll
            for (int mi = 0; mi < 2; mi++)
                pa[mi] = *(const bf16x8*)&QP[32 * wid + 16 * mi + l15][32 * kk + 8 * l4];
#pragma unroll
            for (int di = 0; di < 4; di++) {
                bf16x8 vf = *(const bf16x8*)&Vs[16 * di + l15][32 * kk + 8 * l4];
#pragma unroll
                for (int mi = 0; mi < 2; mi++)
                    po[mi][di] = __builtin_amdgcn_mfma_f32_16x16x32_bf16(pa[mi], vf, po[mi][di], 0, 0, 0);
            }
        }
    }

    const int bb = bh >> 4, h = bh & 15;
#pragma unroll
    for (int mi = 0; mi < 2; mi++)
#pragma unroll
        for (int r = 0; r < 4; r++) {
            float inv = 1.f / l_run[mi][r];
            int ml = 32 * wid + 16 * mi + 4 * l4 + r;
            size_t base = ((size_t)(bb * SEQ + q0 + ml)) * NDIM + h * DHEAD;
#pragma unroll
            for (int di = 0; di < 4; di++)
                ao[base + 16 * di + l15] = f2bf(po[mi][di][r] * inv);
        }
}

// ---------------- K5: bf16 MFMA output GEMM + bias ----------------
__global__ __launch_bounds__(256) void out_gemm_mfma(
    const unsigned short* __restrict__ A, const unsigned short* __restrict__ BT,
    const float* __restrict__ bias, float* __restrict__ out) {
    __shared__ short As[128][40];
    __shared__ short Bs[128][40];
    const int t = threadIdx.x;
    const int lane = t & 63, wid = t >> 6;
    const int wr = wid >> 1, wc = wid & 1;
    const int l15 = lane & 15, l4 = lane >> 4;
    const int m0 = blockIdx.x * 128, n0 = blockIdx.y * 128;
    const int ar = t >> 1, as = (t & 1) * 16;

    f32x4 acc[4][4];
#pragma unroll
    for (int i = 0; i < 4; i++)
#pragma unroll
        for (int j = 0; j < 4; j++) acc[i][j] = (f32x4){0.f, 0.f, 0.f, 0.f};

    const unsigned short* ag = A + (size_t)(m0 + ar) * NDIM + as;
    const unsigned short* bg = BT + (size_t)(n0 + ar) * NDIM + as;

    for (int k0 = 0; k0 < NDIM; k0 += 32) {
        ushort8 a0 = *(const ushort8*)(ag + k0);
        ushort8 a1 = *(const ushort8*)(ag + k0 + 8);
        ushort8 b0 = *(const ushort8*)(bg + k0);
        ushort8 b1 = *(const ushort8*)(bg + k0 + 8);
        __syncthreads();
        *(ushort8*)&As[ar][as] = a0;
        *(ushort8*)&As[ar][as + 8] = a1;
        *(ushort8*)&Bs[ar][as] = b0;
        *(ushort8*)&Bs[ar][as + 8] = b1;
        __syncthreads();
        bf16x8 af[4];
#pragma unroll
        for (int mi = 0; mi < 4; mi++)
            af[mi] = *(const bf16x8*)&As[64 * wr + 16 * mi + l15][8 * l4];
#pragma unroll
        for (int ni = 0; ni < 4; ni++) {
            bf16x8 bfr = *(const bf16x8*)&Bs[64 * wc + 16 * ni + l15][8 * l4];
#pragma unroll
            for (int mi = 0; mi < 4; mi++)
                acc[mi][ni] = __builtin_amdgcn_mfma_f32_16x16x32_bf16(af[mi], bfr, acc[mi][ni], 0, 0, 0);
        }
    }

    const int nb = n0 + 64 * wc;
    const int mb = m0 + 64 * wr;
    float bw[4];
#pragma unroll
    for (int ni = 0; ni < 4; ni++) bw[ni] = bias[nb + 16 * ni + l15];
#pragma unroll
    for (int mi = 0; mi < 4; mi++)
#pragma unroll
        for (int r = 0; r < 4; r++) {
            int m = mb + 16 * mi + 4 * l4 + r;
            float* orow = out + (size_t)m * NDIM + nb;
#pragma unroll
            for (int ni = 0; ni < 4; ni++)
                orow[16 * ni + l15] = acc[mi][ni][r] + bw[ni];
        }
}

extern "C" void kernel_launch(void* const* d_in, const int* in_sizes, int n_in,
                              void* d_out, int out_size, void* d_ws, size_t ws_size,
                              hipStream_t stream) {
    const float* x       = (const float*)d_in[0];
    const float* norm_g  = (const float*)d_in[1];
    const float* norm_b  = (const float*)d_in[2];
    const float* w_qkv   = (const float*)d_in[3];
    const float* normk_g = (const float*)d_in[4];
    const float* normk_b = (const float*)d_in[5];
    const float* normv_g = (const float*)d_in[6];
    const float* normv_b = (const float*)d_in[7];
    const float* w_out   = (const float*)d_in[8];
    const float* b_out   = (const float*)d_in[9];
    float* out = (float*)d_out;

    char* p = (char*)d_ws;
    unsigned short* xn  = (unsigned short*)p; p += (size_t)NROWS * NDIM * 2;
    unsigned short* wT  = (unsigned short*)p; p += (size_t)QKVN * NDIM * 2;
    unsigned short* woT = (unsigned short*)p; p += (size_t)NDIM * NDIM * 2;
    unsigned short* qb  = (unsigned short*)p; p += (size_t)NROWS * NDIM * 2;
    unsigned short* kb  = (unsigned short*)p; p += (size_t)NROWS * NDIM * 2;
    unsigned short* vt  = (unsigned short*)p; p += (size_t)NROWS * NDIM * 2;
    unsigned short* ao  = (unsigned short*)p; p += (size_t)NROWS * NDIM * 2;

    ln_norm_kernel<<<NROWS, 256, 0, stream>>>(x, norm_g, norm_b, xn);
    wtrans_kernel<<<dim3(NDIM / 32, QKVN / 32), 256, 0, stream>>>(w_qkv, wT, QKVN);
    wtrans_kernel<<<dim3(NDIM / 32, NDIM / 32), 256, 0, stream>>>(w_out, woT, NDIM);
    qkv_gemm_mfma<<<dim3(NROWS / 128, QKVN / 128), 256, 0, stream>>>(
        xn, wT, normk_g, normk_b, normv_g, normv_b, qb, kb, vt);
    attn_mfma<<<dim3(SEQ / 128, 64), 256, 0, stream>>>(qb, kb, vt, ao);
    out_gemm_mfma<<<dim3(NROWS / 128, NDIM / 128), 256, 0, stream>>>(ao, woT, b_out, out);
}

// Round 4
// 323.026 us; speedup vs baseline: 6.1297x; 1.2675x over previous
//
#include <hip/hip_runtime.h>
#include <math.h>

#define SEQ 2048
#define NDIM 1024
#define HEADS 16
#define DHEAD 64
#define NROWS 8192
#define QKVN 3072
#define LNEPS 1e-5f
// fold attention scale AND log2(e) into Q so scores are in log2-domain
#define QSCALE (0.125f * 1.44269504088896341f)

typedef __attribute__((ext_vector_type(8))) short bf16x8;
typedef __attribute__((ext_vector_type(8))) unsigned short ushort8;
typedef __attribute__((ext_vector_type(4))) float f32x4;
typedef __attribute__((ext_vector_type(16))) float f32x16;
typedef __attribute__((ext_vector_type(2))) int v2i;
typedef __attribute__((ext_vector_type(4))) int i32x4;

__device__ __forceinline__ unsigned short f2bf(float f) {
    unsigned u = __float_as_uint(f);
    u += 0x7fff + ((u >> 16) & 1);   // RNE
    return (unsigned short)(u >> 16);
}

__device__ __forceinline__ int cvtpk_bf16(float lo, float hi) {
    int r;
    asm volatile("v_cvt_pk_bf16_f32 %0, %1, %2" : "=v"(r) : "v"(lo), "v"(hi));
    return r;
}

// ---------------- K1: fused LayerNorm(x) -> bf16 xn [8192][1024] ----------------
__global__ __launch_bounds__(256) void ln_norm_kernel(const float* __restrict__ x,
                                                      const float* __restrict__ g,
                                                      const float* __restrict__ b,
                                                      unsigned short* __restrict__ xn) {
    int row = blockIdx.x, t = threadIdx.x;
    float4 v = ((const float4*)(x + (size_t)row * NDIM))[t];
    float s = v.x + v.y + v.z + v.w;
    float ss = v.x * v.x + v.y * v.y + v.z * v.z + v.w * v.w;
#pragma unroll
    for (int m = 32; m >= 1; m >>= 1) { s += __shfl_xor(s, m); ss += __shfl_xor(ss, m); }
    __shared__ float r0[4], r1[4];
    if ((t & 63) == 0) { r0[t >> 6] = s; r1[t >> 6] = ss; }
    __syncthreads();
    float S = r0[0] + r0[1] + r0[2] + r0[3];
    float SS = r1[0] + r1[1] + r1[2] + r1[3];
    float mu = S * (1.f / NDIM);
    float rsg = rsqrtf(SS * (1.f / NDIM) - mu * mu + LNEPS);
    float4 gv = ((const float4*)g)[t];
    float4 bv = ((const float4*)b)[t];
    ushort4 o;
    o.x = f2bf((v.x - mu) * rsg * gv.x + bv.x);
    o.y = f2bf((v.y - mu) * rsg * gv.y + bv.y);
    o.z = f2bf((v.z - mu) * rsg * gv.z + bv.z);
    o.w = f2bf((v.w - mu) * rsg * gv.w + bv.w);
    ((ushort4*)(xn + (size_t)row * NDIM))[t] = o;
}

// ---------------- K2: transpose w [1024][N] fp32 -> wT [N][1024] bf16 ----------------
__global__ __launch_bounds__(256) void wtrans_kernel(const float* __restrict__ w,
                                                     unsigned short* __restrict__ wT,
                                                     int N) {
    __shared__ float Tt[32][36];
    int k0 = blockIdx.x * 32, n0 = blockIdx.y * 32;
    int t = threadIdx.x;
    int kr = t >> 3, nc = (t & 7) * 4;
    float4 v = *(const float4*)&w[(size_t)(k0 + kr) * N + n0 + nc];
    Tt[kr][nc + 0] = v.x;
    Tt[kr][nc + 1] = v.y;
    Tt[kr][nc + 2] = v.z;
    Tt[kr][nc + 3] = v.w;
    __syncthreads();
    int nr = t >> 3, kc = (t & 7) * 4;
    ushort4 o;
    o.x = f2bf(Tt[kc + 0][nr]);
    o.y = f2bf(Tt[kc + 1][nr]);
    o.z = f2bf(Tt[kc + 2][nr]);
    o.w = f2bf(Tt[kc + 3][nr]);
    *(ushort4*)&wT[(size_t)(n0 + nr) * NDIM + k0 + kc] = o;
}

// ---------------- K3: bf16 MFMA QKV GEMM, epilogue fuses Q-scale, K-LN, V-LN + V-transpose ----------------
__global__ __launch_bounds__(256) void qkv_gemm_mfma(
    const unsigned short* __restrict__ xn, const unsigned short* __restrict__ wT,
    const float* __restrict__ gk, const float* __restrict__ bk,
    const float* __restrict__ gv, const float* __restrict__ bv,
    unsigned short* __restrict__ qb, unsigned short* __restrict__ kb,
    unsigned short* __restrict__ vt) {
    __shared__ short As[128][40];   // [m][k] pad 32->40
    __shared__ short Bs[128][40];   // [n][k]
    const int t = threadIdx.x;
    const int lane = t & 63, wid = t >> 6;
    const int wr = wid >> 1, wc = wid & 1;
    const int l15 = lane & 15, l4 = lane >> 4;
    const int m0 = blockIdx.x * 128, n0 = blockIdx.y * 128;
    const int ar = t >> 1, as = (t & 1) * 16;

    f32x4 acc[4][4];
#pragma unroll
    for (int i = 0; i < 4; i++)
#pragma unroll
        for (int j = 0; j < 4; j++) acc[i][j] = (f32x4){0.f, 0.f, 0.f, 0.f};

    const unsigned short* ag = xn + (size_t)(m0 + ar) * NDIM + as;
    const unsigned short* bg = wT + (size_t)(n0 + ar) * NDIM + as;

    for (int k0 = 0; k0 < NDIM; k0 += 32) {
        ushort8 a0 = *(const ushort8*)(ag + k0);
        ushort8 a1 = *(const ushort8*)(ag + k0 + 8);
        ushort8 b0 = *(const ushort8*)(bg + k0);
        ushort8 b1 = *(const ushort8*)(bg + k0 + 8);
        __syncthreads();
        *(ushort8*)&As[ar][as] = a0;
        *(ushort8*)&As[ar][as + 8] = a1;
        *(ushort8*)&Bs[ar][as] = b0;
        *(ushort8*)&Bs[ar][as + 8] = b1;
        __syncthreads();
        bf16x8 af[4];
#pragma unroll
        for (int mi = 0; mi < 4; mi++)
            af[mi] = *(const bf16x8*)&As[64 * wr + 16 * mi + l15][8 * l4];
#pragma unroll
        for (int ni = 0; ni < 4; ni++) {
            bf16x8 bfr = *(const bf16x8*)&Bs[64 * wc + 16 * ni + l15][8 * l4];
#pragma unroll
            for (int mi = 0; mi < 4; mi++)
                acc[mi][ni] = __builtin_amdgcn_mfma_f32_16x16x32_bf16(af[mi], bfr, acc[mi][ni], 0, 0, 0);
        }
    }

    const int nblk = n0 + 64 * wc;
    const int which = nblk >> 10;
    const int h = (nblk >> 6) & 15;
    const int mb = m0 + 64 * wr;

    if (which == 0) {  // Q: scale folded in
#pragma unroll
        for (int mi = 0; mi < 4; mi++)
#pragma unroll
            for (int r = 0; r < 4; r++) {
                int m = mb + 16 * mi + 4 * l4 + r;
                int bb = m >> 11, s = m & (SEQ - 1);
                size_t base = ((size_t)(bb * HEADS + h) * SEQ + s) * DHEAD;
#pragma unroll
                for (int ni = 0; ni < 4; ni++)
                    qb[base + 16 * ni + l15] = f2bf(acc[mi][ni][r] * QSCALE);
            }
    } else if (which == 1) {  // K: per-row LN over d
        float gw[4], bw[4];
#pragma unroll
        for (int ni = 0; ni < 4; ni++) { gw[ni] = gk[16 * ni + l15]; bw[ni] = bk[16 * ni + l15]; }
#pragma unroll
        for (int mi = 0; mi < 4; mi++)
#pragma unroll
            for (int r = 0; r < 4; r++) {
                float sum = 0.f, ssum = 0.f;
#pragma unroll
                for (int ni = 0; ni < 4; ni++) { float v = acc[mi][ni][r]; sum += v; ssum += v * v; }
#pragma unroll
                for (int msk = 1; msk <= 8; msk <<= 1) { sum += __shfl_xor(sum, msk); ssum += __shfl_xor(ssum, msk); }
                float mu = sum * (1.f / DHEAD);
                float rsg = rsqrtf(ssum * (1.f / DHEAD) - mu * mu + LNEPS);
                int m = mb + 16 * mi + 4 * l4 + r;
                int bb = m >> 11, s = m & (SEQ - 1);
                size_t base = ((size_t)(bb * HEADS + h) * SEQ + s) * DHEAD;
#pragma unroll
                for (int ni = 0; ni < 4; ni++)
                    kb[base + 16 * ni + l15] = f2bf((acc[mi][ni][r] - mu) * rsg * gw[ni] + bw[ni]);
            }
    } else {  // V: per-row LN then transposed store vt[bh][d][s]
        float gw[4], bw[4];
#pragma unroll
        for (int ni = 0; ni < 4; ni++) { gw[ni] = gv[16 * ni + l15]; bw[ni] = bv[16 * ni + l15]; }
#pragma unroll
        for (int mi = 0; mi < 4; mi++) {
            float mu4[4], rs4[4];
#pragma unroll
            for (int r = 0; r < 4; r++) {
                float sum = 0.f, ssum = 0.f;
#pragma unroll
                for (int ni = 0; ni < 4; ni++) { float v = acc[mi][ni][r]; sum += v; ssum += v * v; }
#pragma unroll
                for (int msk = 1; msk <= 8; msk <<= 1) { sum += __shfl_xor(sum, msk); ssum += __shfl_xor(ssum, msk); }
                float mu = sum * (1.f / DHEAD);
                mu4[r] = mu;
                rs4[r] = rsqrtf(ssum * (1.f / DHEAD) - mu * mu + LNEPS);
            }
            int m = mb + 16 * mi + 4 * l4;
            int bb = m >> 11, s = m & (SEQ - 1);
#pragma unroll
            for (int ni = 0; ni < 4; ni++) {
                ushort4 o;
                o.x = f2bf((acc[mi][ni][0] - mu4[0]) * rs4[0] * gw[ni] + bw[ni]);
                o.y = f2bf((acc[mi][ni][1] - mu4[1]) * rs4[1] * gw[ni] + bw[ni]);
                o.z = f2bf((acc[mi][ni][2] - mu4[2]) * rs4[2] * gw[ni] + bw[ni]);
                o.w = f2bf((acc[mi][ni][3] - mu4[3]) * rs4[3] * gw[ni] + bw[ni]);
                *(ushort4*)&vt[((size_t)(bb * HEADS + h) * DHEAD + 16 * ni + l15) * SEQ + s] = o;
            }
        }
    }
}

// ---------------- K4: 32x32 swapped-operand MFMA flash attention ----------------
// Block = 128 q rows of one (b,h); 4 waves x 32 q. KVBLK=64.
// S^T = mfma(K, Q): lane owns q = lane&31; 32 kv values in regs (in-lane softmax).
// P -> bf16 via cvt_pk + permlane32_swap (no LDS round-trip).
// O^T = mfma(V^T, P): col = q = lane&31 -> per-lane m/l state throughout.
__global__ __launch_bounds__(256) void attn_mfma32(
    const unsigned short* __restrict__ qb, const unsigned short* __restrict__ kb,
    const unsigned short* __restrict__ vt, unsigned short* __restrict__ ao) {
    __shared__ short Ks[64 * 64];   // [kv][d], 16B units XOR-swizzled by (row&7)
    __shared__ short Vs[64 * 68];   // [d][kv], pad 64->68 shorts
    const int t = threadIdx.x;
    const int lane = t & 63, wid = t >> 6;
    const int l31 = lane & 31, l5 = lane >> 5;
    // bijective XCD swizzle over 1024 blocks (16 qblk x 64 bh)
    const int flat = blockIdx.x;
    const int swz = (flat & 7) * 128 + (flat >> 3);
    const int bh = swz >> 4;
    const int q0 = (swz & 15) * 128;
    const unsigned short* Qg = qb + (size_t)bh * SEQ * DHEAD;
    const unsigned short* Kg = kb + (size_t)bh * SEQ * DHEAD;
    const unsigned short* Vg = vt + (size_t)bh * DHEAD * SEQ;

    // Q fragments (B-operand): col=q=l31, k = 16*s + 8*l5 + j
    const int qrow = q0 + 32 * wid + l31;
    bf16x8 qf[4];
#pragma unroll
    for (int s = 0; s < 4; s++)
        qf[s] = *(const bf16x8*)&Qg[(size_t)qrow * DHEAD + 16 * s + 8 * l5];

    f32x16 po[2];
#pragma unroll
    for (int i = 0; i < 16; i++) { po[0][i] = 0.f; po[1][i] = 0.f; }
    float m_run = -1e30f, l_run = 0.f;

    // staging map: thread -> (row = t>>3 (+32), 16B unit = t&7)
    const int srow = t >> 3, su = t & 7;
    const int ku = ((su ^ (srow & 7)) * 8);   // (srow+32)&7 == srow&7
    ushort8 kA, kB, vA, vB;
    kA = *(const ushort8*)&Kg[(size_t)srow * DHEAD + su * 8];
    kB = *(const ushort8*)&Kg[(size_t)(srow + 32) * DHEAD + su * 8];
    vA = *(const ushort8*)&Vg[(size_t)srow * SEQ + su * 8];
    vB = *(const ushort8*)&Vg[(size_t)(srow + 32) * SEQ + su * 8];

    for (int kv0 = 0; kv0 < SEQ; kv0 += 64) {
        __syncthreads();   // prev tile LDS reads done
        *(ushort8*)&Ks[srow * 64 + ku] = kA;
        *(ushort8*)&Ks[(srow + 32) * 64 + ku] = kB;
        *(ushort8*)&Vs[srow * 68 + su * 8] = vA;
        *(ushort8*)&Vs[(srow + 32) * 68 + su * 8] = vB;
        __syncthreads();
        if (kv0 + 64 < SEQ) {  // T14: issue next tile's loads before compute
            int nk = kv0 + 64;
            kA = *(const ushort8*)&Kg[(size_t)(nk + srow) * DHEAD + su * 8];
            kB = *(const ushort8*)&Kg[(size_t)(nk + srow + 32) * DHEAD + su * 8];
            vA = *(const ushort8*)&Vg[(size_t)srow * SEQ + nk + su * 8];
            vB = *(const ushort8*)&Vg[(size_t)(srow + 32) * SEQ + nk + su * 8];
        }

        // S^T = K . Q^T  (two 32-kv sub-tiles)
        f32x16 sc[2];
#pragma unroll
        for (int i = 0; i < 16; i++) { sc[0][i] = 0.f; sc[1][i] = 0.f; }
#pragma unroll
        for (int sub = 0; sub < 2; sub++) {
            const int r = 32 * sub + l31;
            const int rx = r & 7;
#pragma unroll
            for (int s = 0; s < 4; s++) {
                bf16x8 kf = *(const bf16x8*)&Ks[r * 64 + ((2 * s + l5) ^ rx) * 8];
                sc[sub] = __builtin_amdgcn_mfma_f32_32x32x16_bf16(kf, qf[s], sc[sub], 0, 0, 0);
            }
        }

        // in-lane softmax over 32 kv (+1 swap for the l5-pair)
        float t8[8];
#pragma unroll
        for (int i = 0; i < 8; i++)
            t8[i] = fmaxf(fmaxf(sc[0][i], sc[0][i + 8]), fmaxf(sc[1][i], sc[1][i + 8]));
        float mx = fmaxf(fmaxf(fmaxf(t8[0], t8[1]), fmaxf(t8[2], t8[3])),
                         fmaxf(fmaxf(t8[4], t8[5]), fmaxf(t8[6], t8[7])));
        mx = fmaxf(mx, __shfl_xor(mx, 32));
        if (__any(mx > m_run + 8.f)) {   // defer-max: rescale rarely
            float mn = fmaxf(m_run, mx);
            float al = exp2f(m_run - mn);
            m_run = mn;
            l_run *= al;
#pragma unroll
            for (int i = 0; i < 16; i++) { po[0][i] *= al; po[1][i] *= al; }
        }
        float p[32];
#pragma unroll
        for (int i = 0; i < 16; i++) {
            p[i] = exp2f(sc[0][i] - m_run);
            p[16 + i] = exp2f(sc[1][i] - m_run);
        }
        float sA = 0.f, sB = 0.f, sC = 0.f, sD = 0.f;
#pragma unroll
        for (int i = 0; i < 32; i += 4) { sA += p[i]; sB += p[i + 1]; sC += p[i + 2]; sD += p[i + 3]; }
        float sum = (sA + sB) + (sC + sD);
        sum += __shfl_xor(sum, 32);
        l_run += sum;

        // O^T += V^T . P  (4 kv-slots of 16)
#pragma unroll
        for (int slot = 0; slot < 4; slot++) {
            const int b = 8 * slot;
            int w0 = cvtpk_bf16(p[b + 0], p[b + 1]);
            int w1 = cvtpk_bf16(p[b + 2], p[b + 3]);
            int w4 = cvtpk_bf16(p[b + 4], p[b + 5]);
            int w5 = cvtpk_bf16(p[b + 6], p[b + 7]);
            v2i e0 = __builtin_amdgcn_permlane32_swap(w0, w4, false, false);
            v2i e1 = __builtin_amdgcn_permlane32_swap(w1, w5, false, false);
            i32x4 fw;
            fw.x = e0.x; fw.y = e1.x; fw.z = e0.y; fw.w = e1.y;
            bf16x8 pf = __builtin_bit_cast(bf16x8, fw);
#pragma unroll
            for (int di = 0; di < 2; di++) {
                bf16x8 vf = *(const bf16x8*)&Vs[(32 * di + l31) * 68 + 16 * slot + 8 * l5];
                po[di] = __builtin_amdgcn_mfma_f32_32x32x16_bf16(vf, pf, po[di], 0, 0, 0);
            }
        }
    }

    const int bb = bh >> 4, h = bh & 15;
    float inv = 1.f / l_run;
    size_t rb = (size_t)(bb * SEQ + qrow) * NDIM + h * DHEAD;
#pragma unroll
    for (int di = 0; di < 2; di++)
#pragma unroll
        for (int g = 0; g < 4; g++) {
            ushort4 o;
            o.x = f2bf(po[di][4 * g + 0] * inv);
            o.y = f2bf(po[di][4 * g + 1] * inv);
            o.z = f2bf(po[di][4 * g + 2] * inv);
            o.w = f2bf(po[di][4 * g + 3] * inv);
            *(ushort4*)&ao[rb + 32 * di + 8 * g + 4 * l5] = o;
        }
}

// ---------------- K5: bf16 MFMA output GEMM + bias ----------------
__global__ __launch_bounds__(256) void out_gemm_mfma(
    const unsigned short* __restrict__ A, const unsigned short* __restrict__ BT,
    const float* __restrict__ bias, float* __restrict__ out) {
    __shared__ short As[128][40];
    __shared__ short Bs[128][40];
    const int t = threadIdx.x;
    const int lane = t & 63, wid = t >> 6;
    const int wr = wid >> 1, wc = wid & 1;
    const int l15 = lane & 15, l4 = lane >> 4;
    const int m0 = blockIdx.x * 128, n0 = blockIdx.y * 128;
    const int ar = t >> 1, as = (t & 1) * 16;

    f32x4 acc[4][4];
#pragma unroll
    for (int i = 0; i < 4; i++)
#pragma unroll
        for (int j = 0; j < 4; j++) acc[i][j] = (f32x4){0.f, 0.f, 0.f, 0.f};

    const unsigned short* ag = A + (size_t)(m0 + ar) * NDIM + as;
    const unsigned short* bg = BT + (size_t)(n0 + ar) * NDIM + as;

    for (int k0 = 0; k0 < NDIM; k0 += 32) {
        ushort8 a0 = *(const ushort8*)(ag + k0);
        ushort8 a1 = *(const ushort8*)(ag + k0 + 8);
        ushort8 b0 = *(const ushort8*)(bg + k0);
        ushort8 b1 = *(const ushort8*)(bg + k0 + 8);
        __syncthreads();
        *(ushort8*)&As[ar][as] = a0;
        *(ushort8*)&As[ar][as + 8] = a1;
        *(ushort8*)&Bs[ar][as] = b0;
        *(ushort8*)&Bs[ar][as + 8] = b1;
        __syncthreads();
        bf16x8 af[4];
#pragma unroll
        for (int mi = 0; mi < 4; mi++)
            af[mi] = *(const bf16x8*)&As[64 * wr + 16 * mi + l15][8 * l4];
#pragma unroll
        for (int ni = 0; ni < 4; ni++) {
            bf16x8 bfr = *(const bf16x8*)&Bs[64 * wc + 16 * ni + l15][8 * l4];
#pragma unroll
            for (int mi = 0; mi < 4; mi++)
                acc[mi][ni] = __builtin_amdgcn_mfma_f32_16x16x32_bf16(af[mi], bfr, acc[mi][ni], 0, 0, 0);
        }
    }

    const int nb = n0 + 64 * wc;
    const int mb = m0 + 64 * wr;
    float bw[4];
#pragma unroll
    for (int ni = 0; ni < 4; ni++) bw[ni] = bias[nb + 16 * ni + l15];
#pragma unroll
    for (int mi = 0; mi < 4; mi++)
#pragma unroll
        for (int r = 0; r < 4; r++) {
            int m = mb + 16 * mi + 4 * l4 + r;
            float* orow = out + (size_t)m * NDIM + nb;
#pragma unroll
            for (int ni = 0; ni < 4; ni++)
                orow[16 * ni + l15] = acc[mi][ni][r] + bw[ni];
        }
}

extern "C" void kernel_launch(void* const* d_in, const int* in_sizes, int n_in,
                              void* d_out, int out_size, void* d_ws, size_t ws_size,
                              hipStream_t stream) {
    const float* x       = (const float*)d_in[0];
    const float* norm_g  = (const float*)d_in[1];
    const float* norm_b  = (const float*)d_in[2];
    const float* w_qkv   = (const float*)d_in[3];
    const float* normk_g = (const float*)d_in[4];
    const float* normk_b = (const float*)d_in[5];
    const float* normv_g = (const float*)d_in[6];
    const float* normv_b = (const float*)d_in[7];
    const float* w_out   = (const float*)d_in[8];
    const float* b_out   = (const float*)d_in[9];
    float* out = (float*)d_out;

    char* p = (char*)d_ws;
    unsigned short* xn  = (unsigned short*)p; p += (size_t)NROWS * NDIM * 2;
    unsigned short* wT  = (unsigned short*)p; p += (size_t)QKVN * NDIM * 2;
    unsigned short* woT = (unsigned short*)p; p += (size_t)NDIM * NDIM * 2;
    unsigned short* qb  = (unsigned short*)p; p += (size_t)NROWS * NDIM * 2;
    unsigned short* kb  = (unsigned short*)p; p += (size_t)NROWS * NDIM * 2;
    unsigned short* vt  = (unsigned short*)p; p += (size_t)NROWS * NDIM * 2;
    unsigned short* ao  = (unsigned short*)p; p += (size_t)NROWS * NDIM * 2;

    ln_norm_kernel<<<NROWS, 256, 0, stream>>>(x, norm_g, norm_b, xn);
    wtrans_kernel<<<dim3(NDIM / 32, QKVN / 32), 256, 0, stream>>>(w_qkv, wT, QKVN);
    wtrans_kernel<<<dim3(NDIM / 32, NDIM / 32), 256, 0, stream>>>(w_out, woT, NDIM);
    qkv_gemm_mfma<<<dim3(NROWS / 128, QKVN / 128), 256, 0, stream>>>(
        xn, wT, normk_g, normk_b, normv_g, normv_b, qb, kb, vt);
    attn_mfma32<<<1024, 256, 0, stream>>>(qb, kb, vt, ao);
    out_gemm_mfma<<<dim3(NROWS / 128, NDIM / 128), 256, 0, stream>>>(ao, woT, b_out, out);
}

// Round 5
// 302.386 us; speedup vs baseline: 6.5481x; 1.0683x over previous
//
#include <hip/hip_runtime.h>
#include <math.h>

#define SEQ 2048
#define NDIM 1024
#define HEADS 16
#define DHEAD 64
#define NROWS 8192
#define QKVN 3072
#define LNEPS 1e-5f
// fold attention scale AND log2(e) into Q so scores are in log2-domain
#define QSCALE (0.125f * 1.44269504088896341f)

typedef __attribute__((ext_vector_type(8))) short bf16x8;
typedef __attribute__((ext_vector_type(8))) unsigned short ushort8;
typedef __attribute__((ext_vector_type(2))) float f32x2;
typedef __attribute__((ext_vector_type(4))) float f32x4;
typedef __attribute__((ext_vector_type(16))) float f32x16;
typedef __attribute__((ext_vector_type(2))) int v2i;
typedef __attribute__((ext_vector_type(4))) int i32x4;

#define F3(a, b, c) fmaxf(fmaxf((a), (b)), (c))

__device__ __forceinline__ unsigned short f2bf(float f) {
    unsigned u = __float_as_uint(f);
    u += 0x7fff + ((u >> 16) & 1);   // RNE
    return (unsigned short)(u >> 16);
}

__device__ __forceinline__ int cvtpk_bf16(float lo, float hi) {
    int r;
    asm volatile("v_cvt_pk_bf16_f32 %0, %1, %2" : "=v"(r) : "v"(lo), "v"(hi));
    return r;
}

// ---------------- K1: fused LayerNorm(x) -> bf16 xn [8192][1024] ----------------
__global__ __launch_bounds__(256) void ln_norm_kernel(const float* __restrict__ x,
                                                      const float* __restrict__ g,
                                                      const float* __restrict__ b,
                                                      unsigned short* __restrict__ xn) {
    int row = blockIdx.x, t = threadIdx.x;
    float4 v = ((const float4*)(x + (size_t)row * NDIM))[t];
    float s = v.x + v.y + v.z + v.w;
    float ss = v.x * v.x + v.y * v.y + v.z * v.z + v.w * v.w;
#pragma unroll
    for (int m = 32; m >= 1; m >>= 1) { s += __shfl_xor(s, m); ss += __shfl_xor(ss, m); }
    __shared__ float r0[4], r1[4];
    if ((t & 63) == 0) { r0[t >> 6] = s; r1[t >> 6] = ss; }
    __syncthreads();
    float S = r0[0] + r0[1] + r0[2] + r0[3];
    float SS = r1[0] + r1[1] + r1[2] + r1[3];
    float mu = S * (1.f / NDIM);
    float rsg = rsqrtf(SS * (1.f / NDIM) - mu * mu + LNEPS);
    float4 gv = ((const float4*)g)[t];
    float4 bv = ((const float4*)b)[t];
    ushort4 o;
    o.x = f2bf((v.x - mu) * rsg * gv.x + bv.x);
    o.y = f2bf((v.y - mu) * rsg * gv.y + bv.y);
    o.z = f2bf((v.z - mu) * rsg * gv.z + bv.z);
    o.w = f2bf((v.w - mu) * rsg * gv.w + bv.w);
    ((ushort4*)(xn + (size_t)row * NDIM))[t] = o;
}

// ---------------- K2: transpose w [1024][N] fp32 -> wT [N][1024] bf16 ----------------
__global__ __launch_bounds__(256) void wtrans_kernel(const float* __restrict__ w,
                                                     unsigned short* __restrict__ wT,
                                                     int N) {
    __shared__ float Tt[32][36];
    int k0 = blockIdx.x * 32, n0 = blockIdx.y * 32;
    int t = threadIdx.x;
    int kr = t >> 3, nc = (t & 7) * 4;
    float4 v = *(const float4*)&w[(size_t)(k0 + kr) * N + n0 + nc];
    Tt[kr][nc + 0] = v.x;
    Tt[kr][nc + 1] = v.y;
    Tt[kr][nc + 2] = v.z;
    Tt[kr][nc + 3] = v.w;
    __syncthreads();
    int nr = t >> 3, kc = (t & 7) * 4;
    ushort4 o;
    o.x = f2bf(Tt[kc + 0][nr]);
    o.y = f2bf(Tt[kc + 1][nr]);
    o.z = f2bf(Tt[kc + 2][nr]);
    o.w = f2bf(Tt[kc + 3][nr]);
    *(ushort4*)&wT[(size_t)(n0 + nr) * NDIM + k0 + kc] = o;
}

// ---------------- K3: bf16 MFMA QKV GEMM, epilogue fuses Q-scale, K-LN, V-LN + V-transpose ----------------
__global__ __launch_bounds__(256) void qkv_gemm_mfma(
    const unsigned short* __restrict__ xn, const unsigned short* __restrict__ wT,
    const float* __restrict__ gk, const float* __restrict__ bk,
    const float* __restrict__ gv, const float* __restrict__ bv,
    unsigned short* __restrict__ qb, unsigned short* __restrict__ kb,
    unsigned short* __restrict__ vt) {
    __shared__ short As[128][40];   // [m][k] pad 32->40
    __shared__ short Bs[128][40];   // [n][k]
    const int t = threadIdx.x;
    const int lane = t & 63, wid = t >> 6;
    const int wr = wid >> 1, wc = wid & 1;
    const int l15 = lane & 15, l4 = lane >> 4;
    const int m0 = blockIdx.x * 128, n0 = blockIdx.y * 128;
    const int ar = t >> 1, as = (t & 1) * 16;

    f32x4 acc[4][4];
#pragma unroll
    for (int i = 0; i < 4; i++)
#pragma unroll
        for (int j = 0; j < 4; j++) acc[i][j] = (f32x4){0.f, 0.f, 0.f, 0.f};

    const unsigned short* ag = xn + (size_t)(m0 + ar) * NDIM + as;
    const unsigned short* bg = wT + (size_t)(n0 + ar) * NDIM + as;

    // prologue loads for k0 = 0 (T14: tile k+1 loads issue during compute of k)
    ushort8 a0 = *(const ushort8*)(ag);
    ushort8 a1 = *(const ushort8*)(ag + 8);
    ushort8 b0 = *(const ushort8*)(bg);
    ushort8 b1 = *(const ushort8*)(bg + 8);

    for (int k0 = 0; k0 < NDIM; k0 += 32) {
        __syncthreads();
        *(ushort8*)&As[ar][as] = a0;
        *(ushort8*)&As[ar][as + 8] = a1;
        *(ushort8*)&Bs[ar][as] = b0;
        *(ushort8*)&Bs[ar][as + 8] = b1;
        __syncthreads();
        if (k0 + 32 < NDIM) {
            a0 = *(const ushort8*)(ag + k0 + 32);
            a1 = *(const ushort8*)(ag + k0 + 40);
            b0 = *(const ushort8*)(bg + k0 + 32);
            b1 = *(const ushort8*)(bg + k0 + 40);
        }
        bf16x8 af[4];
#pragma unroll
        for (int mi = 0; mi < 4; mi++)
            af[mi] = *(const bf16x8*)&As[64 * wr + 16 * mi + l15][8 * l4];
#pragma unroll
        for (int ni = 0; ni < 4; ni++) {
            bf16x8 bfr = *(const bf16x8*)&Bs[64 * wc + 16 * ni + l15][8 * l4];
#pragma unroll
            for (int mi = 0; mi < 4; mi++)
                acc[mi][ni] = __builtin_amdgcn_mfma_f32_16x16x32_bf16(af[mi], bfr, acc[mi][ni], 0, 0, 0);
        }
    }

    const int nblk = n0 + 64 * wc;
    const int which = nblk >> 10;
    const int h = (nblk >> 6) & 15;
    const int mb = m0 + 64 * wr;

    if (which == 0) {  // Q: scale folded in
#pragma unroll
        for (int mi = 0; mi < 4; mi++)
#pragma unroll
            for (int r = 0; r < 4; r++) {
                int m = mb + 16 * mi + 4 * l4 + r;
                int bb = m >> 11, s = m & (SEQ - 1);
                size_t base = ((size_t)(bb * HEADS + h) * SEQ + s) * DHEAD;
#pragma unroll
                for (int ni = 0; ni < 4; ni++)
                    qb[base + 16 * ni + l15] = f2bf(acc[mi][ni][r] * QSCALE);
            }
    } else if (which == 1) {  // K: per-row LN over d
        float gw[4], bw[4];
#pragma unroll
        for (int ni = 0; ni < 4; ni++) { gw[ni] = gk[16 * ni + l15]; bw[ni] = bk[16 * ni + l15]; }
#pragma unroll
        for (int mi = 0; mi < 4; mi++)
#pragma unroll
            for (int r = 0; r < 4; r++) {
                float sum = 0.f, ssum = 0.f;
#pragma unroll
                for (int ni = 0; ni < 4; ni++) { float v = acc[mi][ni][r]; sum += v; ssum += v * v; }
#pragma unroll
                for (int msk = 1; msk <= 8; msk <<= 1) { sum += __shfl_xor(sum, msk); ssum += __shfl_xor(ssum, msk); }
                float mu = sum * (1.f / DHEAD);
                float rsg = rsqrtf(ssum * (1.f / DHEAD) - mu * mu + LNEPS);
                int m = mb + 16 * mi + 4 * l4 + r;
                int bb = m >> 11, s = m & (SEQ - 1);
                size_t base = ((size_t)(bb * HEADS + h) * SEQ + s) * DHEAD;
#pragma unroll
                for (int ni = 0; ni < 4; ni++)
                    kb[base + 16 * ni + l15] = f2bf((acc[mi][ni][r] - mu) * rsg * gw[ni] + bw[ni]);
            }
    } else {  // V: per-row LN then transposed store vt[bh][d][s]
        float gw[4], bw[4];
#pragma unroll
        for (int ni = 0; ni < 4; ni++) { gw[ni] = gv[16 * ni + l15]; bw[ni] = bv[16 * ni + l15]; }
#pragma unroll
        for (int mi = 0; mi < 4; mi++) {
            float mu4[4], rs4[4];
#pragma unroll
            for (int r = 0; r < 4; r++) {
                float sum = 0.f, ssum = 0.f;
#pragma unroll
                for (int ni = 0; ni < 4; ni++) { float v = acc[mi][ni][r]; sum += v; ssum += v * v; }
#pragma unroll
                for (int msk = 1; msk <= 8; msk <<= 1) { sum += __shfl_xor(sum, msk); ssum += __shfl_xor(ssum, msk); }
                float mu = sum * (1.f / DHEAD);
                mu4[r] = mu;
                rs4[r] = rsqrtf(ssum * (1.f / DHEAD) - mu * mu + LNEPS);
            }
            int m = mb + 16 * mi + 4 * l4;
            int bb = m >> 11, s = m & (SEQ - 1);
#pragma unroll
            for (int ni = 0; ni < 4; ni++) {
                ushort4 o;
                o.x = f2bf((acc[mi][ni][0] - mu4[0]) * rs4[0] * gw[ni] + bw[ni]);
                o.y = f2bf((acc[mi][ni][1] - mu4[1]) * rs4[1] * gw[ni] + bw[ni]);
                o.z = f2bf((acc[mi][ni][2] - mu4[2]) * rs4[2] * gw[ni] + bw[ni]);
                o.w = f2bf((acc[mi][ni][3] - mu4[3]) * rs4[3] * gw[ni] + bw[ni]);
                *(ushort4*)&vt[((size_t)(bb * HEADS + h) * DHEAD + 16 * ni + l15) * SEQ + s] = o;
            }
        }
    }
}

// ---------------- K4: 32x32 swapped-operand MFMA flash attention ----------------
// S^T = mfma(K, Q): lane owns q = lane&31, 32 kv scores in regs.
// Softmax fully in-lane (+1 cross-half shuffle); P->bf16 via cvt_pk+permlane.
// O^T = mfma(V^T, P). VALU-trimmed: loop-invariant zero C-tuple, max3 tree,
// paired f32x2 sums.
__global__ __launch_bounds__(256) void attn_mfma32(
    const unsigned short* __restrict__ qb, const unsigned short* __restrict__ kb,
    const unsigned short* __restrict__ vt, unsigned short* __restrict__ ao) {
    __shared__ short Ks[64 * 64];   // [kv][d], 16B units XOR-swizzled by (row&7)
    __shared__ short Vs[64 * 68];   // [d][kv], pad 64->68 shorts
    const int t = threadIdx.x;
    const int lane = t & 63, wid = t >> 6;
    const int l31 = lane & 31, l5 = lane >> 5;
    const int flat = blockIdx.x;
    const int swz = (flat & 7) * 128 + (flat >> 3);   // bijective XCD chunking
    const int bh = swz >> 4;
    const int q0 = (swz & 15) * 128;
    const unsigned short* Qg = qb + (size_t)bh * SEQ * DHEAD;
    const unsigned short* Kg = kb + (size_t)bh * SEQ * DHEAD;
    const unsigned short* Vg = vt + (size_t)bh * DHEAD * SEQ;

    const int qrow = q0 + 32 * wid + l31;
    bf16x8 qf[4];
#pragma unroll
    for (int s = 0; s < 4; s++)
        qf[s] = *(const bf16x8*)&Qg[(size_t)qrow * DHEAD + 16 * s + 8 * l5];

    f32x16 kZero;
#pragma unroll
    for (int i = 0; i < 16; i++) kZero[i] = 0.f;

    f32x16 po[2];
    po[0] = kZero;
    po[1] = kZero;
    float m_run = -1e30f, l_run = 0.f;

    const int srow = t >> 3, su = t & 7;
    const int ku = ((su ^ (srow & 7)) * 8);
    ushort8 kA, kB, vA, vB;
    kA = *(const ushort8*)&Kg[(size_t)srow * DHEAD + su * 8];
    kB = *(const ushort8*)&Kg[(size_t)(srow + 32) * DHEAD + su * 8];
    vA = *(const ushort8*)&Vg[(size_t)srow * SEQ + su * 8];
    vB = *(const ushort8*)&Vg[(size_t)(srow + 32) * SEQ + su * 8];

    const int rx = l31 & 7;

    for (int kv0 = 0; kv0 < SEQ; kv0 += 64) {
        __syncthreads();
        *(ushort8*)&Ks[srow * 64 + ku] = kA;
        *(ushort8*)&Ks[(srow + 32) * 64 + ku] = kB;
        *(ushort8*)&Vs[srow * 68 + su * 8] = vA;
        *(ushort8*)&Vs[(srow + 32) * 68 + su * 8] = vB;
        __syncthreads();
        if (kv0 + 64 < SEQ) {
            int nk = kv0 + 64;
            kA = *(const ushort8*)&Kg[(size_t)(nk + srow) * DHEAD + su * 8];
            kB = *(const ushort8*)&Kg[(size_t)(nk + srow + 32) * DHEAD + su * 8];
            vA = *(const ushort8*)&Vg[(size_t)srow * SEQ + nk + su * 8];
            vB = *(const ushort8*)&Vg[(size_t)(srow + 32) * SEQ + nk + su * 8];
        }

        // S^T: first MFMA of each sub consumes loop-invariant kZero (no re-zero movs)
        const short* K0 = &Ks[l31 * 64];
        const short* K1 = &Ks[(32 + l31) * 64];
        f32x16 sc0, sc1;
        {
            bf16x8 kf0 = *(const bf16x8*)&K0[((0 + l5) ^ rx) * 8];
            bf16x8 kf1 = *(const bf16x8*)&K1[((0 + l5) ^ rx) * 8];
            sc0 = __builtin_amdgcn_mfma_f32_32x32x16_bf16(kf0, qf[0], kZero, 0, 0, 0);
            sc1 = __builtin_amdgcn_mfma_f32_32x32x16_bf16(kf1, qf[0], kZero, 0, 0, 0);
        }
#pragma unroll
        for (int s = 1; s < 4; s++) {
            bf16x8 kf0 = *(const bf16x8*)&K0[((2 * s + l5) ^ rx) * 8];
            bf16x8 kf1 = *(const bf16x8*)&K1[((2 * s + l5) ^ rx) * 8];
            sc0 = __builtin_amdgcn_mfma_f32_32x32x16_bf16(kf0, qf[s], sc0, 0, 0, 0);
            sc1 = __builtin_amdgcn_mfma_f32_32x32x16_bf16(kf1, qf[s], sc1, 0, 0, 0);
        }

        // max over 32 in-lane scores via v_max3 tree (+1 cross-half shuffle)
        float m0 = F3(sc0[0], sc0[1], sc0[2]);
        float m1 = F3(sc0[3], sc0[4], sc0[5]);
        float m2 = F3(sc0[6], sc0[7], sc0[8]);
        float m3 = F3(sc0[9], sc0[10], sc0[11]);
        float m4 = F3(sc0[12], sc0[13], sc0[14]);
        float m5 = F3(sc0[15], sc1[0], sc1[1]);
        float m6 = F3(sc1[2], sc1[3], sc1[4]);
        float m7 = F3(sc1[5], sc1[6], sc1[7]);
        float m8 = F3(sc1[8], sc1[9], sc1[10]);
        float m9 = F3(sc1[11], sc1[12], sc1[13]);
        float mA = fmaxf(sc1[14], sc1[15]);
        float n0 = F3(m0, m1, m2);
        float n1 = F3(m3, m4, m5);
        float n2 = F3(m6, m7, m8);
        float n3 = F3(m9, mA, n0);
        float mx = F3(n1, n2, n3);
        mx = fmaxf(mx, __shfl_xor(mx, 32));
        if (__any(mx > m_run + 8.f)) {   // defer-max: rare after early tiles
            float mn = fmaxf(m_run, mx);
            float al = exp2f(m_run - mn);
            m_run = mn;
            l_run *= al;
#pragma unroll
            for (int i = 0; i < 16; i++) { po[0][i] *= al; po[1][i] *= al; }
        }

        // P = exp2(S - m), kept as f32x2 pairs (same pairing cvt_pk consumes)
        f32x2 pv[16];
#pragma unroll
        for (int i = 0; i < 8; i++) {
            pv[i].x     = exp2f(sc0[2 * i] - m_run);
            pv[i].y     = exp2f(sc0[2 * i + 1] - m_run);
            pv[8 + i].x = exp2f(sc1[2 * i] - m_run);
            pv[8 + i].y = exp2f(sc1[2 * i + 1] - m_run);
        }
        f32x2 u0 = pv[0] + pv[1],   u1 = pv[2] + pv[3];
        f32x2 u2 = pv[4] + pv[5],   u3 = pv[6] + pv[7];
        f32x2 u4 = pv[8] + pv[9],   u5 = pv[10] + pv[11];
        f32x2 u6 = pv[12] + pv[13], u7 = pv[14] + pv[15];
        f32x2 w0 = (u0 + u1) + (u2 + u3);
        f32x2 w1 = (u4 + u5) + (u6 + u7);
        f32x2 wt = w0 + w1;
        float sum = wt.x + wt.y;
        sum += __shfl_xor(sum, 32);
        l_run += sum;

        // O^T += V^T . P  (4 kv-slots of 16)
#pragma unroll
        for (int slot = 0; slot < 4; slot++) {
            const int b = 4 * slot;
            int c0 = cvtpk_bf16(pv[b + 0].x, pv[b + 0].y);
            int c1 = cvtpk_bf16(pv[b + 1].x, pv[b + 1].y);
            int c4 = cvtpk_bf16(pv[b + 2].x, pv[b + 2].y);
            int c5 = cvtpk_bf16(pv[b + 3].x, pv[b + 3].y);
            v2i e0 = __builtin_amdgcn_permlane32_swap(c0, c4, false, false);
            v2i e1 = __builtin_amdgcn_permlane32_swap(c1, c5, false, false);
            i32x4 fw;
            fw.x = e0.x; fw.y = e1.x; fw.z = e0.y; fw.w = e1.y;
            bf16x8 pf = __builtin_bit_cast(bf16x8, fw);
#pragma unroll
            for (int di = 0; di < 2; di++) {
                bf16x8 vf = *(const bf16x8*)&Vs[(32 * di + l31) * 68 + 16 * slot + 8 * l5];
                po[di] = __builtin_amdgcn_mfma_f32_32x32x16_bf16(vf, pf, po[di], 0, 0, 0);
            }
        }
    }

    const int bb = bh >> 4, h = bh & 15;
    float inv = 1.f / l_run;
    size_t rb = (size_t)(bb * SEQ + qrow) * NDIM + h * DHEAD;
#pragma unroll
    for (int di = 0; di < 2; di++)
#pragma unroll
        for (int g = 0; g < 4; g++) {
            ushort4 o;
            o.x = f2bf(po[di][4 * g + 0] * inv);
            o.y = f2bf(po[di][4 * g + 1] * inv);
            o.z = f2bf(po[di][4 * g + 2] * inv);
            o.w = f2bf(po[di][4 * g + 3] * inv);
            *(ushort4*)&ao[rb + 32 * di + 8 * g + 4 * l5] = o;
        }
}

// ---------------- K5: bf16 MFMA output GEMM + bias ----------------
__global__ __launch_bounds__(256) void out_gemm_mfma(
    const unsigned short* __restrict__ A, const unsigned short* __restrict__ BT,
    const float* __restrict__ bias, float* __restrict__ out) {
    __shared__ short As[128][40];
    __shared__ short Bs[128][40];
    const int t = threadIdx.x;
    const int lane = t & 63, wid = t >> 6;
    const int wr = wid >> 1, wc = wid & 1;
    const int l15 = lane & 15, l4 = lane >> 4;
    const int m0 = blockIdx.x * 128, n0 = blockIdx.y * 128;
    const int ar = t >> 1, as = (t & 1) * 16;

    f32x4 acc[4][4];
#pragma unroll
    for (int i = 0; i < 4; i++)
#pragma unroll
        for (int j = 0; j < 4; j++) acc[i][j] = (f32x4){0.f, 0.f, 0.f, 0.f};

    const unsigned short* ag = A + (size_t)(m0 + ar) * NDIM + as;
    const unsigned short* bg = BT + (size_t)(n0 + ar) * NDIM + as;

    ushort8 a0 = *(const ushort8*)(ag);
    ushort8 a1 = *(const ushort8*)(ag + 8);
    ushort8 b0 = *(const ushort8*)(bg);
    ushort8 b1 = *(const ushort8*)(bg + 8);

    for (int k0 = 0; k0 < NDIM; k0 += 32) {
        __syncthreads();
        *(ushort8*)&As[ar][as] = a0;
        *(ushort8*)&As[ar][as + 8] = a1;
        *(ushort8*)&Bs[ar][as] = b0;
        *(ushort8*)&Bs[ar][as + 8] = b1;
        __syncthreads();
        if (k0 + 32 < NDIM) {
            a0 = *(const ushort8*)(ag + k0 + 32);
            a1 = *(const ushort8*)(ag + k0 + 40);
            b0 = *(const ushort8*)(bg + k0 + 32);
            b1 = *(const ushort8*)(bg + k0 + 40);
        }
        bf16x8 af[4];
#pragma unroll
        for (int mi = 0; mi < 4; mi++)
            af[mi] = *(const bf16x8*)&As[64 * wr + 16 * mi + l15][8 * l4];
#pragma unroll
        for (int ni = 0; ni < 4; ni++) {
            bf16x8 bfr = *(const bf16x8*)&Bs[64 * wc + 16 * ni + l15][8 * l4];
#pragma unroll
            for (int mi = 0; mi < 4; mi++)
                acc[mi][ni] = __builtin_amdgcn_mfma_f32_16x16x32_bf16(af[mi], bfr, acc[mi][ni], 0, 0, 0);
        }
    }

    const int nb = n0 + 64 * wc;
    const int mb = m0 + 64 * wr;
    float bw[4];
#pragma unroll
    for (int ni = 0; ni < 4; ni++) bw[ni] = bias[nb + 16 * ni + l15];
#pragma unroll
    for (int mi = 0; mi < 4; mi++)
#pragma unroll
        for (int r = 0; r < 4; r++) {
            int m = mb + 16 * mi + 4 * l4 + r;
            float* orow = out + (size_t)m * NDIM + nb;
#pragma unroll
            for (int ni = 0; ni < 4; ni++)
                orow[16 * ni + l15] = acc[mi][ni][r] + bw[ni];
        }
}

extern "C" void kernel_launch(void* const* d_in, const int* in_sizes, int n_in,
                              void* d_out, int out_size, void* d_ws, size_t ws_size,
                              hipStream_t stream) {
    const float* x       = (const float*)d_in[0];
    const float* norm_g  = (const float*)d_in[1];
    const float* norm_b  = (const float*)d_in[2];
    const float* w_qkv   = (const float*)d_in[3];
    const float* normk_g = (const float*)d_in[4];
    const float* normk_b = (const float*)d_in[5];
    const float* normv_g = (const float*)d_in[6];
    const float* normv_b = (const float*)d_in[7];
    const float* w_out   = (const float*)d_in[8];
    const float* b_out   = (const float*)d_in[9];
    float* out = (float*)d_out;

    char* p = (char*)d_ws;
    unsigned short* xn  = (unsigned short*)p; p += (size_t)NROWS * NDIM * 2;
    unsigned short* wT  = (unsigned short*)p; p += (size_t)QKVN * NDIM * 2;
    unsigned short* woT = (unsigned short*)p; p += (size_t)NDIM * NDIM * 2;
    unsigned short* qb  = (unsigned short*)p; p += (size_t)NROWS * NDIM * 2;
    unsigned short* kb  = (unsigned short*)p; p += (size_t)NROWS * NDIM * 2;
    unsigned short* vt  = (unsigned short*)p; p += (size_t)NROWS * NDIM * 2;
    unsigned short* ao  = (unsigned short*)p; p += (size_t)NROWS * NDIM * 2;

    ln_norm_kernel<<<NROWS, 256, 0, stream>>>(x, norm_g, norm_b, xn);
    wtrans_kernel<<<dim3(NDIM / 32, QKVN / 32), 256, 0, stream>>>(w_qkv, wT, QKVN);
    wtrans_kernel<<<dim3(NDIM / 32, NDIM / 32), 256, 0, stream>>>(w_out, woT, NDIM);
    qkv_gemm_mfma<<<dim3(NROWS / 128, QKVN / 128), 256, 0, stream>>>(
        xn, wT, normk_g, normk_b, normv_g, normv_b, qb, kb, vt);
    attn_mfma32<<<1024, 256, 0, stream>>>(qb, kb, vt, ao);
    out_gemm_mfma<<<dim3(NROWS / 128, NDIM / 128), 256, 0, stream>>>(ao, woT, b_out, out);
}

// Round 6
// 285.452 us; speedup vs baseline: 6.9366x; 1.0593x over previous
//
#include <hip/hip_runtime.h>
#include <math.h>

#define SEQ 2048
#define NDIM 1024
#define HEADS 16
#define DHEAD 64
#define NROWS 8192
#define QKVN 3072
#define LNEPS 1e-5f
// fold attention scale AND log2(e) into Q so scores are in log2-domain
#define QSCALE (0.125f * 1.44269504088896341f)

typedef __attribute__((ext_vector_type(8))) short bf16x8;
typedef __attribute__((ext_vector_type(8))) unsigned short ushort8;
typedef __attribute__((ext_vector_type(4))) float f32x4;
typedef __attribute__((ext_vector_type(16))) float f32x16;
typedef __attribute__((ext_vector_type(2))) int v2i;
typedef __attribute__((ext_vector_type(4))) int i32x4;

#define F3(a, b, c) fmaxf(fmaxf((a), (b)), (c))

__device__ __forceinline__ unsigned short f2bf(float f) {
    unsigned u = __float_as_uint(f);
    u += 0x7fff + ((u >> 16) & 1);   // RNE
    return (unsigned short)(u >> 16);
}

__device__ __forceinline__ int cvtpk_bf16(float lo, float hi) {
    int r;
    asm volatile("v_cvt_pk_bf16_f32 %0, %1, %2" : "=v"(r) : "v"(lo), "v"(hi));
    return r;
}

// async global->LDS, 16B per lane; per-lane global src, wave-uniform LDS base
__device__ __forceinline__ void gld16(const void* g, void* l) {
    __builtin_amdgcn_global_load_lds(
        (const __attribute__((address_space(1))) unsigned int*)g,
        (__attribute__((address_space(3))) unsigned int*)l, 16, 0, 0);
}

// ---------------- K1: fused LayerNorm(x) -> bf16 xn [8192][1024] ----------------
__global__ __launch_bounds__(256) void ln_norm_kernel(const float* __restrict__ x,
                                                      const float* __restrict__ g,
                                                      const float* __restrict__ b,
                                                      unsigned short* __restrict__ xn) {
    int row = blockIdx.x, t = threadIdx.x;
    float4 v = ((const float4*)(x + (size_t)row * NDIM))[t];
    float s = v.x + v.y + v.z + v.w;
    float ss = v.x * v.x + v.y * v.y + v.z * v.z + v.w * v.w;
#pragma unroll
    for (int m = 32; m >= 1; m >>= 1) { s += __shfl_xor(s, m); ss += __shfl_xor(ss, m); }
    __shared__ float r0[4], r1[4];
    if ((t & 63) == 0) { r0[t >> 6] = s; r1[t >> 6] = ss; }
    __syncthreads();
    float S = r0[0] + r0[1] + r0[2] + r0[3];
    float SS = r1[0] + r1[1] + r1[2] + r1[3];
    float mu = S * (1.f / NDIM);
    float rsg = rsqrtf(SS * (1.f / NDIM) - mu * mu + LNEPS);
    float4 gv = ((const float4*)g)[t];
    float4 bv = ((const float4*)b)[t];
    ushort4 o;
    o.x = f2bf((v.x - mu) * rsg * gv.x + bv.x);
    o.y = f2bf((v.y - mu) * rsg * gv.y + bv.y);
    o.z = f2bf((v.z - mu) * rsg * gv.z + bv.z);
    o.w = f2bf((v.w - mu) * rsg * gv.w + bv.w);
    ((ushort4*)(xn + (size_t)row * NDIM))[t] = o;
}

// ---------------- K2: transpose w [1024][N] fp32 -> wT [N][1024] bf16 ----------------
__global__ __launch_bounds__(256) void wtrans_kernel(const float* __restrict__ w,
                                                     unsigned short* __restrict__ wT,
                                                     int N) {
    __shared__ float Tt[32][36];
    int k0 = blockIdx.x * 32, n0 = blockIdx.y * 32;
    int t = threadIdx.x;
    int kr = t >> 3, nc = (t & 7) * 4;
    float4 v = *(const float4*)&w[(size_t)(k0 + kr) * N + n0 + nc];
    Tt[kr][nc + 0] = v.x;
    Tt[kr][nc + 1] = v.y;
    Tt[kr][nc + 2] = v.z;
    Tt[kr][nc + 3] = v.w;
    __syncthreads();
    int nr = t >> 3, kc = (t & 7) * 4;
    ushort4 o;
    o.x = f2bf(Tt[kc + 0][nr]);
    o.y = f2bf(Tt[kc + 1][nr]);
    o.z = f2bf(Tt[kc + 2][nr]);
    o.w = f2bf(Tt[kc + 3][nr]);
    *(ushort4*)&wT[(size_t)(n0 + nr) * NDIM + k0 + kc] = o;
}

// ---------------- K3: bf16 MFMA QKV GEMM, epilogue fuses Q-scale, K-LN, V-LN + V-transpose ----------------
__global__ __launch_bounds__(256) void qkv_gemm_mfma(
    const unsigned short* __restrict__ xn, const unsigned short* __restrict__ wT,
    const float* __restrict__ gk, const float* __restrict__ bk,
    const float* __restrict__ gv, const float* __restrict__ bv,
    unsigned short* __restrict__ qb, unsigned short* __restrict__ kb,
    unsigned short* __restrict__ vt) {
    __shared__ short As[128][40];   // [m][k] pad 32->40
    __shared__ short Bs[128][40];   // [n][k]
    const int t = threadIdx.x;
    const int lane = t & 63, wid = t >> 6;
    const int wr = wid >> 1, wc = wid & 1;
    const int l15 = lane & 15, l4 = lane >> 4;
    const int m0 = blockIdx.x * 128, n0 = blockIdx.y * 128;
    const int ar = t >> 1, as = (t & 1) * 16;

    f32x4 acc[4][4];
#pragma unroll
    for (int i = 0; i < 4; i++)
#pragma unroll
        for (int j = 0; j < 4; j++) acc[i][j] = (f32x4){0.f, 0.f, 0.f, 0.f};

    const unsigned short* ag = xn + (size_t)(m0 + ar) * NDIM + as;
    const unsigned short* bg = wT + (size_t)(n0 + ar) * NDIM + as;

    ushort8 a0 = *(const ushort8*)(ag);
    ushort8 a1 = *(const ushort8*)(ag + 8);
    ushort8 b0 = *(const ushort8*)(bg);
    ushort8 b1 = *(const ushort8*)(bg + 8);

    for (int k0 = 0; k0 < NDIM; k0 += 32) {
        __syncthreads();
        *(ushort8*)&As[ar][as] = a0;
        *(ushort8*)&As[ar][as + 8] = a1;
        *(ushort8*)&Bs[ar][as] = b0;
        *(ushort8*)&Bs[ar][as + 8] = b1;
        __syncthreads();
        if (k0 + 32 < NDIM) {
            a0 = *(const ushort8*)(ag + k0 + 32);
            a1 = *(const ushort8*)(ag + k0 + 40);
            b0 = *(const ushort8*)(bg + k0 + 32);
            b1 = *(const ushort8*)(bg + k0 + 40);
        }
        bf16x8 af[4];
#pragma unroll
        for (int mi = 0; mi < 4; mi++)
            af[mi] = *(const bf16x8*)&As[64 * wr + 16 * mi + l15][8 * l4];
#pragma unroll
        for (int ni = 0; ni < 4; ni++) {
            bf16x8 bfr = *(const bf16x8*)&Bs[64 * wc + 16 * ni + l15][8 * l4];
#pragma unroll
            for (int mi = 0; mi < 4; mi++)
                acc[mi][ni] = __builtin_amdgcn_mfma_f32_16x16x32_bf16(af[mi], bfr, acc[mi][ni], 0, 0, 0);
        }
    }

    const int nblk = n0 + 64 * wc;
    const int which = nblk >> 10;
    const int h = (nblk >> 6) & 15;
    const int mb = m0 + 64 * wr;

    if (which == 0) {  // Q: scale folded in
#pragma unroll
        for (int mi = 0; mi < 4; mi++)
#pragma unroll
            for (int r = 0; r < 4; r++) {
                int m = mb + 16 * mi + 4 * l4 + r;
                int bb = m >> 11, s = m & (SEQ - 1);
                size_t base = ((size_t)(bb * HEADS + h) * SEQ + s) * DHEAD;
#pragma unroll
                for (int ni = 0; ni < 4; ni++)
                    qb[base + 16 * ni + l15] = f2bf(acc[mi][ni][r] * QSCALE);
            }
    } else if (which == 1) {  // K: per-row LN over d
        float gw[4], bw[4];
#pragma unroll
        for (int ni = 0; ni < 4; ni++) { gw[ni] = gk[16 * ni + l15]; bw[ni] = bk[16 * ni + l15]; }
#pragma unroll
        for (int mi = 0; mi < 4; mi++)
#pragma unroll
            for (int r = 0; r < 4; r++) {
                float sum = 0.f, ssum = 0.f;
#pragma unroll
                for (int ni = 0; ni < 4; ni++) { float v = acc[mi][ni][r]; sum += v; ssum += v * v; }
#pragma unroll
                for (int msk = 1; msk <= 8; msk <<= 1) { sum += __shfl_xor(sum, msk); ssum += __shfl_xor(ssum, msk); }
                float mu = sum * (1.f / DHEAD);
                float rsg = rsqrtf(ssum * (1.f / DHEAD) - mu * mu + LNEPS);
                int m = mb + 16 * mi + 4 * l4 + r;
                int bb = m >> 11, s = m & (SEQ - 1);
                size_t base = ((size_t)(bb * HEADS + h) * SEQ + s) * DHEAD;
#pragma unroll
                for (int ni = 0; ni < 4; ni++)
                    kb[base + 16 * ni + l15] = f2bf((acc[mi][ni][r] - mu) * rsg * gw[ni] + bw[ni]);
            }
    } else {  // V: per-row LN then transposed store vt[bh][d][s]
        float gw[4], bw[4];
#pragma unroll
        for (int ni = 0; ni < 4; ni++) { gw[ni] = gv[16 * ni + l15]; bw[ni] = bv[16 * ni + l15]; }
#pragma unroll
        for (int mi = 0; mi < 4; mi++) {
            float mu4[4], rs4[4];
#pragma unroll
            for (int r = 0; r < 4; r++) {
                float sum = 0.f, ssum = 0.f;
#pragma unroll
                for (int ni = 0; ni < 4; ni++) { float v = acc[mi][ni][r]; sum += v; ssum += v * v; }
#pragma unroll
                for (int msk = 1; msk <= 8; msk <<= 1) { sum += __shfl_xor(sum, msk); ssum += __shfl_xor(ssum, msk); }
                float mu = sum * (1.f / DHEAD);
                mu4[r] = mu;
                rs4[r] = rsqrtf(ssum * (1.f / DHEAD) - mu * mu + LNEPS);
            }
            int m = mb + 16 * mi + 4 * l4;
            int bb = m >> 11, s = m & (SEQ - 1);
#pragma unroll
            for (int ni = 0; ni < 4; ni++) {
                ushort4 o;
                o.x = f2bf((acc[mi][ni][0] - mu4[0]) * rs4[0] * gw[ni] + bw[ni]);
                o.y = f2bf((acc[mi][ni][1] - mu4[1]) * rs4[1] * gw[ni] + bw[ni]);
                o.z = f2bf((acc[mi][ni][2] - mu4[2]) * rs4[2] * gw[ni] + bw[ni]);
                o.w = f2bf((acc[mi][ni][3] - mu4[3]) * rs4[3] * gw[ni] + bw[ni]);
                *(ushort4*)&vt[((size_t)(bb * HEADS + h) * DHEAD + 16 * ni + l15) * SEQ + s] = o;
            }
        }
    }
}

// softmax + PV for one 64-kv group (two 32-kv subtiles S0,S1; V slots SBASE..SBASE+3)
#define SOFTMAX_PV(S0, S1, SBASE)                                                     \
    {                                                                                 \
        float m0_ = F3(S0[0], S0[1], S0[2]);                                          \
        float m1_ = F3(S0[3], S0[4], S0[5]);                                          \
        float m2_ = F3(S0[6], S0[7], S0[8]);                                          \
        float m3_ = F3(S0[9], S0[10], S0[11]);                                        \
        float m4_ = F3(S0[12], S0[13], S0[14]);                                       \
        float m5_ = F3(S0[15], S1[0], S1[1]);                                         \
        float m6_ = F3(S1[2], S1[3], S1[4]);                                          \
        float m7_ = F3(S1[5], S1[6], S1[7]);                                          \
        float m8_ = F3(S1[8], S1[9], S1[10]);                                         \
        float m9_ = F3(S1[11], S1[12], S1[13]);                                       \
        float mA_ = fmaxf(S1[14], S1[15]);                                            \
        float n0_ = F3(m0_, m1_, m2_);                                                \
        float n1_ = F3(m3_, m4_, m5_);                                                \
        float n2_ = F3(m6_, m7_, m8_);                                                \
        float n3_ = F3(m9_, mA_, n0_);                                                \
        float mx_ = F3(n1_, n2_, n3_);                                                \
        mx_ = fmaxf(mx_, __shfl_xor(mx_, 32));                                        \
        if (__any(mx_ > m_run + 8.f)) {                                               \
            float mn_ = fmaxf(m_run, mx_);                                            \
            float al_ = exp2f(m_run - mn_);                                           \
            m_run = mn_;                                                              \
            l_run *= al_;                                                             \
            po0 = po0 * al_;                                                          \
            po1 = po1 * al_;                                                          \
        }                                                                             \
        _Pragma("unroll")                                                             \
        for (int i_ = 0; i_ < 16; ++i_) {                                             \
            S0[i_] = exp2f(S0[i_] - m_run);                                           \
            S1[i_] = exp2f(S1[i_] - m_run);                                           \
        }                                                                             \
        float u0_ = (S0[0] + S0[1]) + (S0[2] + S0[3]);                                \
        float u1_ = (S0[4] + S0[5]) + (S0[6] + S0[7]);                                \
        float u2_ = (S0[8] + S0[9]) + (S0[10] + S0[11]);                              \
        float u3_ = (S0[12] + S0[13]) + (S0[14] + S0[15]);                            \
        float u4_ = (S1[0] + S1[1]) + (S1[2] + S1[3]);                                \
        float u5_ = (S1[4] + S1[5]) + (S1[6] + S1[7]);                                \
        float u6_ = (S1[8] + S1[9]) + (S1[10] + S1[11]);                              \
        float u7_ = (S1[12] + S1[13]) + (S1[14] + S1[15]);                            \
        float sum_ = ((u0_ + u1_) + (u2_ + u3_)) + ((u4_ + u5_) + (u6_ + u7_));       \
        sum_ += __shfl_xor(sum_, 32);                                                 \
        l_run += sum_;                                                                \
        _Pragma("unroll")                                                             \
        for (int js_ = 0; js_ < 4; ++js_) {                                           \
            const f32x16& P_ = (js_ < 2) ? S0 : S1;                                   \
            const int b_ = 8 * (js_ & 1);                                             \
            int c0_ = cvtpk_bf16(P_[b_ + 0], P_[b_ + 1]);                             \
            int c1_ = cvtpk_bf16(P_[b_ + 2], P_[b_ + 3]);                             \
            int c4_ = cvtpk_bf16(P_[b_ + 4], P_[b_ + 5]);                             \
            int c5_ = cvtpk_bf16(P_[b_ + 6], P_[b_ + 7]);                             \
            v2i e0_ = __builtin_amdgcn_permlane32_swap(c0_, c4_, false, false);       \
            v2i e1_ = __builtin_amdgcn_permlane32_swap(c1_, c5_, false, false);       \
            i32x4 fw_;                                                                \
            fw_.x = e0_.x; fw_.y = e1_.x; fw_.z = e0_.y; fw_.w = e1_.y;               \
            bf16x8 pf_ = __builtin_bit_cast(bf16x8, fw_);                             \
            const int vs_ = (SBASE) + js_;                                            \
            bf16x8 vf0_ = *(const bf16x8*)&Vb[(l31) * 128 + (((2 * vs_ + l5) ^ rx16)) * 8];        \
            bf16x8 vf1_ = *(const bf16x8*)&Vb[(32 + l31) * 128 + (((2 * vs_ + l5) ^ rx16)) * 8];   \
            po0 = __builtin_amdgcn_mfma_f32_32x32x16_bf16(vf0_, pf_, po0, 0, 0, 0);   \
            po1 = __builtin_amdgcn_mfma_f32_32x32x16_bf16(vf1_, pf_, po1, 0, 0, 0);   \
        }                                                                             \
    }

// ---------------- K4: 32x32 swapped-operand flash attention, KVBLK=128 ----------------
// Double-buffered LDS via global_load_lds (pre-swizzled per-lane SOURCE, linear dest,
// swizzled read -- rule #21). Per tile: issue all 16 QK MFMAs (A+B groups), then
// softmax-A overlaps B's MFMAs, PV-A overlaps softmax-B. One barrier per 128 kv.
__global__ __launch_bounds__(256) void attn_mfma32(
    const unsigned short* __restrict__ qb, const unsigned short* __restrict__ kb,
    const unsigned short* __restrict__ vt, unsigned short* __restrict__ ao) {
    __shared__ short KsAll[2][128 * 64];   // [kv][8 units], unit u holds global unit u^(kv&7)
    __shared__ short VsAll[2][64 * 128];   // [d][16 units], unit u holds global unit u^(d&15)
    const int t = threadIdx.x;
    const int lane = t & 63, wid = t >> 6;
    const int l31 = lane & 31, l5 = lane >> 5;
    const int flat = blockIdx.x;
    const int swz = (flat & 7) * 128 + (flat >> 3);   // bijective XCD chunking
    const int bh = swz >> 4;
    const int q0 = (swz & 15) * 128;
    const unsigned short* Qg = qb + (size_t)bh * SEQ * DHEAD;
    const unsigned short* Kg = kb + (size_t)bh * SEQ * DHEAD;
    const unsigned short* Vg = vt + (size_t)bh * DHEAD * SEQ;

    const int qrow = q0 + 32 * wid + l31;
    bf16x8 qf[4];
#pragma unroll
    for (int s = 0; s < 4; s++)
        qf[s] = *(const bf16x8*)&Qg[(size_t)qrow * DHEAD + 16 * s + 8 * l5];

    f32x16 kZero;
#pragma unroll
    for (int i = 0; i < 16; i++) kZero[i] = 0.f;
    f32x16 po0 = kZero, po1 = kZero;
    float m_run = -1e30f, l_run = 0.f;

    const int rx = l31 & 7;
    const int rx16 = l31 & 15;
    // staging lane constants (inverse-swizzled global source, linear LDS dest)
    const int krow_l = lane >> 3;                       // K: row offset within 8-row call
    const int ku_l = (lane & 7) ^ (lane >> 3);          // K: global 16B-unit
    const int vrow_l = lane >> 4;                       // V: row offset within 4-row call

    // prologue: stage tile 0 into buffer 0
#pragma unroll
    for (int c = 0; c < 4; c++) {
        int R = 32 * wid + 8 * c;
        gld16(&Kg[(size_t)(R + krow_l) * DHEAD + ku_l * 8], &KsAll[0][R * 64]);
    }
#pragma unroll
    for (int c = 0; c < 4; c++) {
        int D = 16 * wid + 4 * c;
        int d = D + vrow_l;
        int u = (lane & 15) ^ (d & 15);
        gld16(&Vg[(size_t)d * SEQ + u * 8], &VsAll[0][D * 128]);
    }

    int cur = 0;
    for (int kv0 = 0; kv0 < SEQ; kv0 += 128) {
        __syncthreads();   // vmcnt(0) drained by compiler: tile `cur` resident
        const short* Kb = KsAll[cur];
        const short* Vb = VsAll[cur];
        if (kv0 + 128 < SEQ) {   // stage next tile into other buffer (overlaps compute)
            short* Kn = KsAll[cur ^ 1];
            short* Vn = VsAll[cur ^ 1];
            const int nk = kv0 + 128;
#pragma unroll
            for (int c = 0; c < 4; c++) {
                int R = 32 * wid + 8 * c;
                gld16(&Kg[(size_t)(nk + R + krow_l) * DHEAD + ku_l * 8], &Kn[R * 64]);
            }
#pragma unroll
            for (int c = 0; c < 4; c++) {
                int D = 16 * wid + 4 * c;
                int d = D + vrow_l;
                int u = (lane & 15) ^ (d & 15);
                gld16(&Vg[(size_t)d * SEQ + nk + u * 8], &Vn[D * 128]);
            }
        }

        // QK: all 4 subtiles issued before any softmax (MFMA/VALU overlap)
        const short* K0 = &Kb[l31 * 64];
        const short* K1 = K0 + 32 * 64;
        const short* K2 = K0 + 64 * 64;
        const short* K3 = K0 + 96 * 64;
        f32x16 sA0, sA1, sB0, sB1;
        {
            bf16x8 f0 = *(const bf16x8*)&K0[((0 + l5) ^ rx) * 8];
            bf16x8 f1 = *(const bf16x8*)&K1[((0 + l5) ^ rx) * 8];
            sA0 = __builtin_amdgcn_mfma_f32_32x32x16_bf16(f0, qf[0], kZero, 0, 0, 0);
            sA1 = __builtin_amdgcn_mfma_f32_32x32x16_bf16(f1, qf[0], kZero, 0, 0, 0);
        }
#pragma unroll
        for (int s = 1; s < 4; s++) {
            bf16x8 f0 = *(const bf16x8*)&K0[((2 * s + l5) ^ rx) * 8];
            bf16x8 f1 = *(const bf16x8*)&K1[((2 * s + l5) ^ rx) * 8];
            sA0 = __builtin_amdgcn_mfma_f32_32x32x16_bf16(f0, qf[s], sA0, 0, 0, 0);
            sA1 = __builtin_amdgcn_mfma_f32_32x32x16_bf16(f1, qf[s], sA1, 0, 0, 0);
        }
        {
            bf16x8 g0 = *(const bf16x8*)&K2[((0 + l5) ^ rx) * 8];
            bf16x8 g1 = *(const bf16x8*)&K3[((0 + l5) ^ rx) * 8];
            sB0 = __builtin_amdgcn_mfma_f32_32x32x16_bf16(g0, qf[0], kZero, 0, 0, 0);
            sB1 = __builtin_amdgcn_mfma_f32_32x32x16_bf16(g1, qf[0], kZero, 0, 0, 0);
        }
#pragma unroll
        for (int s = 1; s < 4; s++) {
            bf16x8 g0 = *(const bf16x8*)&K2[((2 * s + l5) ^ rx) * 8];
            bf16x8 g1 = *(const bf16x8*)&K3[((2 * s + l5) ^ rx) * 8];
            sB0 = __builtin_amdgcn_mfma_f32_32x32x16_bf16(g0, qf[s], sB0, 0, 0, 0);
            sB1 = __builtin_amdgcn_mfma_f32_32x32x16_bf16(g1, qf[s], sB1, 0, 0, 0);
        }

        SOFTMAX_PV(sA0, sA1, 0);   // VALU here overlaps B's QK MFMAs in the pipe
        SOFTMAX_PV(sB0, sB1, 4);   // VALU here overlaps PV-A MFMAs
        cur ^= 1;
    }

    const int bb = bh >> 4, h = bh & 15;
    float inv = 1.f / l_run;
    size_t rb = (size_t)(bb * SEQ + qrow) * NDIM + h * DHEAD;
#pragma unroll
    for (int g = 0; g < 4; g++) {
        ushort4 o;
        o.x = f2bf(po0[4 * g + 0] * inv);
        o.y = f2bf(po0[4 * g + 1] * inv);
        o.z = f2bf(po0[4 * g + 2] * inv);
        o.w = f2bf(po0[4 * g + 3] * inv);
        *(ushort4*)&ao[rb + 8 * g + 4 * l5] = o;
    }
#pragma unroll
    for (int g = 0; g < 4; g++) {
        ushort4 o;
        o.x = f2bf(po1[4 * g + 0] * inv);
        o.y = f2bf(po1[4 * g + 1] * inv);
        o.z = f2bf(po1[4 * g + 2] * inv);
        o.w = f2bf(po1[4 * g + 3] * inv);
        *(ushort4*)&ao[rb + 32 + 8 * g + 4 * l5] = o;
    }
}

// ---------------- K5: bf16 MFMA output GEMM + bias ----------------
__global__ __launch_bounds__(256) void out_gemm_mfma(
    const unsigned short* __restrict__ A, const unsigned short* __restrict__ BT,
    const float* __restrict__ bias, float* __restrict__ out) {
    __shared__ short As[128][40];
    __shared__ short Bs[128][40];
    const int t = threadIdx.x;
    const int lane = t & 63, wid = t >> 6;
    const int wr = wid >> 1, wc = wid & 1;
    const int l15 = lane & 15, l4 = lane >> 4;
    const int m0 = blockIdx.x * 128, n0 = blockIdx.y * 128;
    const int ar = t >> 1, as = (t & 1) * 16;

    f32x4 acc[4][4];
#pragma unroll
    for (int i = 0; i < 4; i++)
#pragma unroll
        for (int j = 0; j < 4; j++) acc[i][j] = (f32x4){0.f, 0.f, 0.f, 0.f};

    const unsigned short* ag = A + (size_t)(m0 + ar) * NDIM + as;
    const unsigned short* bg = BT + (size_t)(n0 + ar) * NDIM + as;

    ushort8 a0 = *(const ushort8*)(ag);
    ushort8 a1 = *(const ushort8*)(ag + 8);
    ushort8 b0 = *(const ushort8*)(bg);
    ushort8 b1 = *(const ushort8*)(bg + 8);

    for (int k0 = 0; k0 < NDIM; k0 += 32) {
        __syncthreads();
        *(ushort8*)&As[ar][as] = a0;
        *(ushort8*)&As[ar][as + 8] = a1;
        *(ushort8*)&Bs[ar][as] = b0;
        *(ushort8*)&Bs[ar][as + 8] = b1;
        __syncthreads();
        if (k0 + 32 < NDIM) {
            a0 = *(const ushort8*)(ag + k0 + 32);
            a1 = *(const ushort8*)(ag + k0 + 40);
            b0 = *(const ushort8*)(bg + k0 + 32);
            b1 = *(const ushort8*)(bg + k0 + 40);
        }
        bf16x8 af[4];
#pragma unroll
        for (int mi = 0; mi < 4; mi++)
            af[mi] = *(const bf16x8*)&As[64 * wr + 16 * mi + l15][8 * l4];
#pragma unroll
        for (int ni = 0; ni < 4; ni++) {
            bf16x8 bfr = *(const bf16x8*)&Bs[64 * wc + 16 * ni + l15][8 * l4];
#pragma unroll
            for (int mi = 0; mi < 4; mi++)
                acc[mi][ni] = __builtin_amdgcn_mfma_f32_16x16x32_bf16(af[mi], bfr, acc[mi][ni], 0, 0, 0);
        }
    }

    const int nb = n0 + 64 * wc;
    const int mb = m0 + 64 * wr;
    float bw[4];
#pragma unroll
    for (int ni = 0; ni < 4; ni++) bw[ni] = bias[nb + 16 * ni + l15];
#pragma unroll
    for (int mi = 0; mi < 4; mi++)
#pragma unroll
        for (int r = 0; r < 4; r++) {
            int m = mb + 16 * mi + 4 * l4 + r;
            float* orow = out + (size_t)m * NDIM + nb;
#pragma unroll
            for (int ni = 0; ni < 4; ni++)
                orow[16 * ni + l15] = acc[mi][ni][r] + bw[ni];
        }
}

extern "C" void kernel_launch(void* const* d_in, const int* in_sizes, int n_in,
                              void* d_out, int out_size, void* d_ws, size_t ws_size,
                              hipStream_t stream) {
    const float* x       = (const float*)d_in[0];
    const float* norm_g  = (const float*)d_in[1];
    const float* norm_b  = (const float*)d_in[2];
    const float* w_qkv   = (const float*)d_in[3];
    const float* normk_g = (const float*)d_in[4];
    const float* normk_b = (const float*)d_in[5];
    const float* normv_g = (const float*)d_in[6];
    const float* normv_b = (const float*)d_in[7];
    const float* w_out   = (const float*)d_in[8];
    const float* b_out   = (const float*)d_in[9];
    float* out = (float*)d_out;

    char* p = (char*)d_ws;
    unsigned short* xn  = (unsigned short*)p; p += (size_t)NROWS * NDIM * 2;
    unsigned short* wT  = (unsigned short*)p; p += (size_t)QKVN * NDIM * 2;
    unsigned short* woT = (unsigned short*)p; p += (size_t)NDIM * NDIM * 2;
    unsigned short* qb  = (unsigned short*)p; p += (size_t)NROWS * NDIM * 2;
    unsigned short* kb  = (unsigned short*)p; p += (size_t)NROWS * NDIM * 2;
    unsigned short* vt  = (unsigned short*)p; p += (size_t)NROWS * NDIM * 2;
    unsigned short* ao  = (unsigned short*)p; p += (size_t)NROWS * NDIM * 2;

    ln_norm_kernel<<<NROWS, 256, 0, stream>>>(x, norm_g, norm_b, xn);
    wtrans_kernel<<<dim3(NDIM / 32, QKVN / 32), 256, 0, stream>>>(w_qkv, wT, QKVN);
    wtrans_kernel<<<dim3(NDIM / 32, NDIM / 32), 256, 0, stream>>>(w_out, woT, NDIM);
    qkv_gemm_mfma<<<dim3(NROWS / 128, QKVN / 128), 256, 0, stream>>>(
        xn, wT, normk_g, normk_b, normv_g, normv_b, qb, kb, vt);
    attn_mfma32<<<1024, 256, 0, stream>>>(qb, kb, vt, ao);
    out_gemm_mfma<<<dim3(NROWS / 128, NDIM / 128), 256, 0, stream>>>(ao, woT, b_out, out);
}